// Round 15
// baseline (576.717 us; speedup 1.0000x reference)
//
#include <hip/hip_runtime.h>
#include <math.h>

#define Bb   4
#define Ss   16
#define Nn   2048
#define Ff   32
#define Ee   16384
#define EFf  8
#define Hh   64
#define HB2  32
#define E2c  (Ee + Nn)          // 18432
#define RTOT (Bb*Ss*Nn)         // 131072 (64 graphs x 2048)
#define Mm   (Ss*Nn)            // 32768
#define CST  68                 // cbuf row stride (bank-friendly, 16B aligned)

typedef __attribute__((ext_vector_type(8))) short short8;
typedef __attribute__((ext_vector_type(4))) float f32x4;
#define MFMA16 __builtin_amdgcn_mfma_f32_16x16x32_bf16

__device__ __forceinline__ float sigf(float x) { return 1.f / (1.f + __expf(-x)); }
__device__ __forceinline__ float tanhfast(float x) { return 2.f / (1.f + __expf(-2.f * x)) - 1.f; }

__device__ __forceinline__ void split_bf16(float x, unsigned short& h, unsigned short& l) {
  unsigned u = __float_as_uint(x);
  unsigned r = (u + 0x7FFFu + ((u >> 16) & 1u)) >> 16;
  h = (unsigned short)r;
  float rest = x - __uint_as_float(r << 16);
  unsigned u2 = __float_as_uint(rest);
  l = (unsigned short)((u2 + 0x7FFFu + ((u2 >> 16) & 1u)) >> 16);
}

template <int PAT>
__device__ __forceinline__ float xorf(float v) {
  return __int_as_float(__builtin_amdgcn_ds_swizzle(__float_as_int(v), PAT));
}
// xor8 (DPP row_ror:8) + xor16 (swizzle) + xor32 (shfl)
__device__ __forceinline__ float red8(float v) {
  int x = __builtin_amdgcn_update_dpp(0, __float_as_int(v), 0x128, 0xF, 0xF, true);
  v += __int_as_float(x);
  v += xorf<0x401F>(v);
  v += __shfl_xor(v, 32, 64);
  return v;
}
// reduce across 8 consecutive lanes: xor1, xor2 (DPP quads), xor4 (swizzle)
__device__ __forceinline__ float redlogit(float v) {
  int x;
  x = __builtin_amdgcn_update_dpp(0, __float_as_int(v), 0xB1, 0xF, 0xF, true);
  v += __int_as_float(x);
  x = __builtin_amdgcn_update_dpp(0, __float_as_int(v), 0x4E, 0xF, 0xF, true);
  v += __int_as_float(x);
  v += xorf<0x101F>(v);
  return v;
}

// ---------------------------------------------------------------------------
__global__ __launch_bounds__(256) void k_loop_accum(
    const int* __restrict__ ei, const float* __restrict__ ea,
    float* __restrict__ cntF, float* __restrict__ loopA) {
  int idx = blockIdx.x * 256 + threadIdx.x;
  int e = idx >> 3, j = idx & 7;
  int d = ei[Ee + e];
  atomicAdd(&loopA[d * EFf + j], ea[idx]);
  if (j == 0) atomicAdd(&cntF[d], 1.0f);
}

// ---------------------------------------------------------------------------
__global__ __launch_bounds__(256) void k_scan(
    const float* __restrict__ cntF, int* __restrict__ offs) {
  __shared__ int partial[256];
  int tid = threadIdx.x;
  int base = tid * 8;
  int vals[8];
  int s = 0;
  for (int i = 0; i < 8; ++i) {
    int c = (int)cntF[base + i] + 1;
    vals[i] = c;
    s += c;
  }
  partial[tid] = s;
  __syncthreads();
  for (int off = 1; off < 256; off <<= 1) {
    int v = partial[tid];
    int add = (tid >= off) ? partial[tid - off] : 0;
    __syncthreads();
    partial[tid] = v + add;
    __syncthreads();
  }
  int run = (tid == 0) ? 0 : partial[tid - 1];
  for (int i = 0; i < 8; ++i) {
    offs[base + i] = run;
    run += vals[i];
  }
  if (tid == 255) offs[Nn] = run;
}

__global__ __launch_bounds__(256) void k_scatter(
    const int* __restrict__ ei, const int* __restrict__ offs,
    int* __restrict__ fillI, int* __restrict__ posOf, int* __restrict__ srcA) {
  int e = blockIdx.x * 256 + threadIdx.x;
  if (e >= E2c) return;
  int d = (e < Ee) ? ei[Ee + e] : (e - Ee);
  int s = (e < Ee) ? ei[e]      : (e - Ee);
  int pos = offs[d] + atomicAdd(&fillI[d], 1);
  posOf[e] = pos;
  srcA[pos] = s;
}

// ---------------------------------------------------------------------------
// Pre-split + pre-swizzle weights into MFMA B-fragment order (R9 layout).
// ---------------------------------------------------------------------------
__global__ __launch_bounds__(256) void k_wprep(
    const float* __restrict__ Wl, const float* __restrict__ Wr,
    const float* __restrict__ Wih, const float* __restrict__ Whh,
    unsigned short* __restrict__ WXhi, unsigned short* __restrict__ WXlo,
    unsigned short* __restrict__ WGhi, unsigned short* __restrict__ WGlo) {
  int idx = blockIdx.x * 256 + threadIdx.x;   // 65536 total
  if (idx < 16384) {
    int j = idx & 7, lane = (idx >> 3) & 63, kh = (idx >> 9) & 1;
    int t = (idx >> 10) & 7, l = idx >> 13;
    int n = t * 16 + (lane & 15);
    int k = kh * 32 + ((lane >> 4) << 3) + j;
    const float* W = (n < 64) ? (Wl + (size_t)l * 4096) : (Wr + (size_t)l * 4096);
    float v = W[k * 64 + (n & 63)];
    unsigned short h, lo;
    split_bf16(v, h, lo);
    WXhi[idx] = h; WXlo[idx] = lo;
  } else {
    int i2 = idx - 16384;                     // < 49152
    int j = i2 & 7, lane = (i2 >> 3) & 63, kh = (i2 >> 9) & 1;
    int t = (i2 >> 10) % 24, l = i2 / 24576;
    int n = t * 16 + (lane & 15);
    int k = kh * 32 + ((lane >> 4) << 3) + j;
    int g = n >> 6, c = n & 63;
    const float* W = (g < 3) ? (Wih + (size_t)l * 12288 + (size_t)(g * 64 + c) * 64)
                             : (Whh + (size_t)l * 12288 + (size_t)((g - 3) * 64 + c) * 64);
    float v = W[k];
    unsigned short h, lo;
    split_bf16(v, h, lo);
    WGhi[i2] = h; WGlo[i2] = lo;
  }
}

// ---------------------------------------------------------------------------
// ep for BOTH layers; self-loop mean division folded in. blockIdx.y = layer.
// ---------------------------------------------------------------------------
__global__ __launch_bounds__(256) void k_ep(
    const float* __restrict__ ea, const float* __restrict__ loopA,
    const float* __restrict__ We, const int* __restrict__ posOf,
    const float* __restrict__ cntF, float* __restrict__ EPc) {
  __shared__ float wlds[EFf * Hh];
  int tid = threadIdx.x;
  int l = blockIdx.y;
  const float* Wel = We + (size_t)l * EFf * Hh;
  if (tid < EFf * Hh) wlds[tid] = Wel[tid];
  if (tid + 256 < EFf * Hh) wlds[tid + 256] = Wel[tid + 256];
  __syncthreads();
  int idx = blockIdx.x * 256 + tid;
  int e = idx >> 6, j = idx & 63;
  const float* a = (e < Ee) ? (ea + (size_t)e * EFf) : (loopA + (size_t)(e - Ee) * EFf);
  float acc = 0.f;
#pragma unroll
  for (int k = 0; k < EFf; ++k) acc += a[k] * wlds[k * Hh + j];
  if (e >= Ee) acc /= fmaxf(cntF[e - Ee], 1.0f);
  EPc[(size_t)l * E2c * Hh + (((size_t)posOf[e]) << 6) + j] = acc;
}

// ---------------------------------------------------------------------------
// proj (R5 version): thread = 2 rows x 16 cols. grid (RTOT/512, 4)
// ---------------------------------------------------------------------------
__global__ __launch_bounds__(256) void k_proj(
    const float* __restrict__ X, const float* __restrict__ Wp,
    const float* __restrict__ bp, float* __restrict__ Out) {
  __shared__ float w[32 * 16];
  int tid = threadIdx.x;
  int j0 = blockIdx.y << 4;
  for (int idx = tid; idx < 32 * 16; idx += 256)
    w[idx] = Wp[((idx >> 4) << 6) + j0 + (idx & 15)];
  __syncthreads();
  int r0 = (blockIdx.x << 9) + tid;
  float acc[2][16];
#pragma unroll
  for (int jj = 0; jj < 16; ++jj) { float b = bp[j0 + jj]; acc[0][jj] = b; acc[1][jj] = b; }
  const float* x0 = X + ((size_t)r0 << 5);
  const float* x1 = x0 + (256 << 5);
  for (int kc = 0; kc < 8; ++kc) {
    float4 a0 = *(const float4*)(x0 + 4 * kc);
    float4 a1 = *(const float4*)(x1 + 4 * kc);
    float a0a[4] = {a0.x, a0.y, a0.z, a0.w};
    float a1a[4] = {a1.x, a1.y, a1.z, a1.w};
#pragma unroll
    for (int q = 0; q < 4; ++q) {
      const float4* wp4 = (const float4*)(w + ((4 * kc + q) << 4));
#pragma unroll
      for (int q4 = 0; q4 < 4; ++q4) {
        float4 wv = wp4[q4];
        acc[0][4*q4+0] = fmaf(a0a[q], wv.x, acc[0][4*q4+0]);
        acc[0][4*q4+1] = fmaf(a0a[q], wv.y, acc[0][4*q4+1]);
        acc[0][4*q4+2] = fmaf(a0a[q], wv.z, acc[0][4*q4+2]);
        acc[0][4*q4+3] = fmaf(a0a[q], wv.w, acc[0][4*q4+3]);
        acc[1][4*q4+0] = fmaf(a1a[q], wv.x, acc[1][4*q4+0]);
        acc[1][4*q4+1] = fmaf(a1a[q], wv.y, acc[1][4*q4+1]);
        acc[1][4*q4+2] = fmaf(a1a[q], wv.z, acc[1][4*q4+2]);
        acc[1][4*q4+3] = fmaf(a1a[q], wv.w, acc[1][4*q4+3]);
      }
    }
  }
#pragma unroll
  for (int rr = 0; rr < 2; ++rr) {
    float* op = Out + (((size_t)(r0 + 256 * rr)) << 6) + j0;
#pragma unroll
    for (int q4 = 0; q4 < 4; ++q4)
      *(float4*)(op + 4 * q4) = make_float4(acc[rr][4*q4], acc[rr][4*q4+1], acc[rr][4*q4+2], acc[rr][4*q4+3]);
  }
}

// ---------------------------------------------------------------------------
// XL/XR via bf16x3 MFMA; vectorized staging; C routed through dedicated
// padded LDS buffer, then coalesced float4 stores. (R14, measured good.)
// ---------------------------------------------------------------------------
__global__ __launch_bounds__(256) void k_xlr_mm(
    const float* __restrict__ X,
    const unsigned short* __restrict__ WXhi, const unsigned short* __restrict__ WXlo,
    const float* __restrict__ bl_, const float* __restrict__ br_,
    float* __restrict__ XL, float* __restrict__ XR) {
  __shared__ unsigned short ahi[4096], alo[4096];
  __shared__ float cbuf[64 * CST];
  int tid = threadIdx.x, lane = tid & 63, wv = tid >> 6;
  size_t m0 = (size_t)blockIdx.x << 6;
#pragma unroll
  for (int it = 0; it < 2; ++it) {
    int task = (it << 8) + tid;
    int row = task >> 3, cOct = task & 7;
    const float* src = X + ((m0 + row) << 6) + (cOct << 3);
    float4 a = *(const float4*)src;
    float4 b = *(const float4*)(src + 4);
    float va[8] = {a.x, a.y, a.z, a.w, b.x, b.y, b.z, b.w};
    short8 hv, lv;
#pragma unroll
    for (int j = 0; j < 8; ++j) {
      unsigned short hs, ls;
      split_bf16(va[j], hs, ls);
      hv[j] = (short)hs; lv[j] = (short)ls;
    }
    int f = ((cOct >> 2) * 4 + (row >> 4)) * 64 + ((cOct & 3) << 4) + (row & 15);
    *(short8*)&ahi[f << 3] = hv;
    *(short8*)&alo[f << 3] = lv;
  }
  __syncthreads();
  short8 Ah0 = *(const short8*)&ahi[((0 + wv) << 6 | lane) << 3];
  short8 Al0 = *(const short8*)&alo[((0 + wv) << 6 | lane) << 3];
  short8 Ah1 = *(const short8*)&ahi[((4 + wv) << 6 | lane) << 3];
  short8 Al1 = *(const short8*)&alo[((4 + wv) << 6 | lane) << 3];
  int nl = lane & 15;
  f32x4 acc[8];
#pragma unroll
  for (int t = 0; t < 8; ++t) {
    int n = t * 16 + nl;
    float b = (n < 64) ? bl_[n] : br_[n - 64];
    acc[t] = (f32x4){b, b, b, b};
  }
#pragma unroll
  for (int t = 0; t < 8; ++t) {
    const short8* bh0p = (const short8*)(WXhi + ((t << 1) << 9)) + lane;
    const short8* bl0p = (const short8*)(WXlo + ((t << 1) << 9)) + lane;
    const short8* bh1p = (const short8*)(WXhi + (((t << 1) + 1) << 9)) + lane;
    const short8* bl1p = (const short8*)(WXlo + (((t << 1) + 1) << 9)) + lane;
    short8 bh0 = *bh0p, bl0 = *bl0p, bh1 = *bh1p, bl1 = *bl1p;
    acc[t] = MFMA16(Ah0, bh0, acc[t], 0, 0, 0);
    acc[t] = MFMA16(Ah0, bl0, acc[t], 0, 0, 0);
    acc[t] = MFMA16(Al0, bh0, acc[t], 0, 0, 0);
    acc[t] = MFMA16(Ah1, bh1, acc[t], 0, 0, 0);
    acc[t] = MFMA16(Ah1, bl1, acc[t], 0, 0, 0);
    acc[t] = MFMA16(Al1, bh1, acc[t], 0, 0, 0);
  }
  int rbase = (wv << 4) + ((lane >> 4) << 2);
#pragma unroll
  for (int half = 0; half < 2; ++half) {
    __syncthreads();
#pragma unroll
    for (int tt = 0; tt < 4; ++tt) {
      int t = (half << 2) + tt;
#pragma unroll
      for (int reg = 0; reg < 4; ++reg)
        cbuf[(rbase + reg) * CST + (tt << 4) + nl] = acc[t][reg];
    }
    __syncthreads();
    float* dst = half ? XR : XL;
#pragma unroll
    for (int i = 0; i < 4; ++i) {
      int idx = (i << 10) + (tid << 2);
      int row = idx >> 6, col = idx & 63;
      *(float4*)(dst + ((m0 + row) << 6) + col) = *(float4*)&cbuf[row * CST + col];
    }
  }
}

// ---------------------------------------------------------------------------
// GATv2 v6: block = (dst d, graph octet q). Each wave handles graphs
// q*8+wv and q*8+wv+4. L2 window = 8 XL slabs (4 MB). 16384 blocks.
// ---------------------------------------------------------------------------
__global__ __launch_bounds__(256) void k_gat(
    const float* __restrict__ XL, float* __restrict__ XR_HG,
    const float* __restrict__ EPc, const int* __restrict__ offs,
    const int* __restrict__ srcA,
    const float* __restrict__ att, const float* __restrict__ gbl) {
  int d = blockIdx.x;
  int q = blockIdx.y;
  int tid = threadIdx.x;
  int wv = tid >> 6, lane = tid & 63;
  int eSub = lane >> 3, hOct = lane & 7;
  int hb = hOct << 3;
  float at[8], gv[8];
  {
    float4 a0 = *(const float4*)(att + hb);
    float4 a1 = *(const float4*)(att + hb + 4);
    float4 g0v = *(const float4*)(gbl + hb);
    float4 g1v = *(const float4*)(gbl + hb + 4);
    at[0]=a0.x; at[1]=a0.y; at[2]=a0.z; at[3]=a0.w;
    at[4]=a1.x; at[5]=a1.y; at[6]=a1.z; at[7]=a1.w;
    gv[0]=g0v.x; gv[1]=g0v.y; gv[2]=g0v.z; gv[3]=g0v.w;
    gv[4]=g1v.x; gv[5]=g1v.y; gv[6]=g1v.z; gv[7]=g1v.w;
  }
  int p0 = offs[d], p1 = offs[d + 1];
  int nE = p1 - p0;
  int nCh = (nE + 7) >> 3;
  int g0 = (q << 3) + wv;
  int g1 = g0 + 4;
  size_t rowA = ((size_t)(g0 * Nn + d)) << 6;
  size_t rowB = ((size_t)(g1 * Nn + d)) << 6;
  float xrA[8], xrB[8];
  {
    float4 a = *(const float4*)(XR_HG + rowA + hb);
    float4 b = *(const float4*)(XR_HG + rowA + hb + 4);
    float4 c = *(const float4*)(XR_HG + rowB + hb);
    float4 e = *(const float4*)(XR_HG + rowB + hb + 4);
    xrA[0]=a.x; xrA[1]=a.y; xrA[2]=a.z; xrA[3]=a.w; xrA[4]=b.x; xrA[5]=b.y; xrA[6]=b.z; xrA[7]=b.w;
    xrB[0]=c.x; xrB[1]=c.y; xrB[2]=c.z; xrB[3]=c.w; xrB[4]=e.x; xrB[5]=e.y; xrB[6]=e.z; xrB[7]=e.w;
  }
  const float* XA = XL + (((size_t)g0 * Nn) << 6);
  const float* XB = XL + (((size_t)g1 * Nn) << 6);
  float SsA = 0.f, SsB = 0.f;
  float accA[8], accB[8];
#pragma unroll
  for (int j = 0; j < 8; ++j) { accA[j] = 0.f; accB[j] = 0.f; }
  for (int c = 0; c < nCh; ++c) {
    int p = (c << 3) + eSub;
    int pc = p < nE ? p : nE - 1;
    int s = srcA[p0 + pc];
    const float* epp = EPc + (((size_t)(p0 + pc)) << 6) + hb;
    float4 e0 = *(const float4*)epp;
    float4 e1 = *(const float4*)(epp + 4);
    float ep[8] = {e0.x, e0.y, e0.z, e0.w, e1.x, e1.y, e1.z, e1.w};
    const float* xap = XA + ((size_t)s << 6) + hb;
    const float* xbp = XB + ((size_t)s << 6) + hb;
    float4 xa0 = *(const float4*)xap, xa1 = *(const float4*)(xap + 4);
    float4 xb0 = *(const float4*)xbp, xb1 = *(const float4*)(xbp + 4);
    float xA[8] = {xa0.x, xa0.y, xa0.z, xa0.w, xa1.x, xa1.y, xa1.z, xa1.w};
    float xB[8] = {xb0.x, xb0.y, xb0.z, xb0.w, xb1.x, xb1.y, xb1.z, xb1.w};
    float vA = 0.f, vB = 0.f;
#pragma unroll
    for (int j = 0; j < 8; ++j) {
      float mA = xA[j] + xrA[j] + ep[j];
      mA = fmaxf(mA, 0.2f * mA);
      vA = fmaf(mA, at[j], vA);
      float mB = xB[j] + xrB[j] + ep[j];
      mB = fmaxf(mB, 0.2f * mB);
      vB = fmaf(mB, at[j], vB);
    }
    vA = redlogit(vA);
    vB = redlogit(vB);
    float wA = (p < nE) ? __expf(vA) : 0.f;
    float wB = (p < nE) ? __expf(vB) : 0.f;
    SsA += wA; SsB += wB;
#pragma unroll
    for (int j = 0; j < 8; ++j) {
      accA[j] = fmaf(wA, xA[j], accA[j]);
      accB[j] = fmaf(wB, xB[j], accB[j]);
    }
  }
  SsA = red8(SsA); SsB = red8(SsB);
#pragma unroll
  for (int j = 0; j < 8; ++j) { accA[j] = red8(accA[j]); accB[j] = red8(accB[j]); }
  if (eSub == 0) {
    float invA = 1.f / SsA, invB = 1.f / SsB;
    float* opA = XR_HG + rowA + hb;
    float* opB = XR_HG + rowB + hb;
    *(float4*)(opA)     = make_float4(fmaf(accA[0], invA, gv[0]), fmaf(accA[1], invA, gv[1]),
                                      fmaf(accA[2], invA, gv[2]), fmaf(accA[3], invA, gv[3]));
    *(float4*)(opA + 4) = make_float4(fmaf(accA[4], invA, gv[4]), fmaf(accA[5], invA, gv[5]),
                                      fmaf(accA[6], invA, gv[6]), fmaf(accA[7], invA, gv[7]));
    *(float4*)(opB)     = make_float4(fmaf(accB[0], invB, gv[0]), fmaf(accB[1], invB, gv[1]),
                                      fmaf(accB[2], invB, gv[2]), fmaf(accB[3], invB, gv[3]));
    *(float4*)(opB + 4) = make_float4(fmaf(accB[4], invB, gv[4]), fmaf(accB[5], invB, gv[5]),
                                      fmaf(accB[6], invB, gv[6]), fmaf(accB[7], invB, gv[7]));
  }
}

// ---------------------------------------------------------------------------
// Fused per-layer GRU: 4 t-steps in one kernel. h carried in cbuf (fp32);
// P-fragments re-split from cbuf in-register; hv read from own cell.
// Block = 64 rows, 4 waves. grid Mm/64.
// ---------------------------------------------------------------------------
__global__ __launch_bounds__(256) void k_gru_layer(
    const float* __restrict__ hg_all,     // [4][Mm][64]
    const unsigned short* __restrict__ WGhi, const unsigned short* __restrict__ WGlo,
    const float* __restrict__ bih, const float* __restrict__ bhh,
    float* __restrict__ hout_all) {       // [4][Mm][64]
  __shared__ unsigned short ghi[4096], glo[4096];   // 16 KB
  __shared__ float cbuf[64 * CST];                  // 17.4 KB (h state)
  int tid = threadIdx.x, lane = tid & 63, wv = tid >> 6;
  size_t m0 = (size_t)blockIdx.x << 6;
  int nl = lane & 15;
  int rbase = (wv << 4) + ((lane >> 4) << 2);
  int mrow = (wv << 4) + nl;               // A-fragment row for this lane
  int kq = (lane >> 4) << 3;               // A-fragment k-quad base

#pragma unroll 1
  for (int t = 0; t < 4; ++t) {
    // stage hg_t (coalesced -> fragment order)
    const float* hg = hg_all + (((size_t)t * Mm + m0) << 6);
#pragma unroll
    for (int it = 0; it < 2; ++it) {
      int task = (it << 8) + tid;
      int row = task >> 3, cOct = task & 7;
      const float* src = hg + (row << 6) + (cOct << 3);
      float4 a = *(const float4*)src;
      float4 b = *(const float4*)(src + 4);
      float va[8] = {a.x, a.y, a.z, a.w, b.x, b.y, b.z, b.w};
      short8 hv8, lv8;
#pragma unroll
      for (int j = 0; j < 8; ++j) {
        unsigned short hs, ls;
        split_bf16(va[j], hs, ls);
        hv8[j] = (short)hs; lv8[j] = (short)ls;
      }
      int f = ((cOct >> 2) * 4 + (row >> 4)) * 64 + ((cOct & 3) << 4) + (row & 15);
      *(short8*)&ghi[f << 3] = hv8;
      *(short8*)&glo[f << 3] = lv8;
    }
    // P-fragments from cbuf (h_{t-1}); reads must precede epilogue overwrites
    short8 Ph0, Pl0, Ph1, Pl1;
    if (t > 0) {
      const float* pr = &cbuf[mrow * CST];
      float4 a0 = *(const float4*)(pr + kq);
      float4 a1 = *(const float4*)(pr + kq + 4);
      float4 b0 = *(const float4*)(pr + 32 + kq);
      float4 b1 = *(const float4*)(pr + 32 + kq + 4);
      float f0[8] = {a0.x, a0.y, a0.z, a0.w, a1.x, a1.y, a1.z, a1.w};
      float f1[8] = {b0.x, b0.y, b0.z, b0.w, b1.x, b1.y, b1.z, b1.w};
#pragma unroll
      for (int j = 0; j < 8; ++j) {
        unsigned short hs, ls;
        split_bf16(f0[j], hs, ls);
        Ph0[j] = (short)hs; Pl0[j] = (short)ls;
        split_bf16(f1[j], hs, ls);
        Ph1[j] = (short)hs; Pl1[j] = (short)ls;
      }
    }
    __syncthreads();
    short8 Gh0 = *(const short8*)&ghi[((0 + wv) << 6 | lane) << 3];
    short8 Gl0 = *(const short8*)&glo[((0 + wv) << 6 | lane) << 3];
    short8 Gh1 = *(const short8*)&ghi[((4 + wv) << 6 | lane) << 3];
    short8 Gl1 = *(const short8*)&glo[((4 + wv) << 6 | lane) << 3];
    f32x4 acc[24];
#pragma unroll
    for (int tt = 0; tt < 24; ++tt) {
      int g = tt >> 2;
      int c = ((tt & 3) << 4) + nl;
      float b = (g < 3) ? bih[(g << 6) + c] : bhh[((g - 3) << 6) + c];
      acc[tt] = (f32x4){b, b, b, b};
    }
#pragma unroll
    for (int tt = 0; tt < 12; ++tt) {
      const short8* bh0p = (const short8*)(WGhi + ((tt << 1) << 9)) + lane;
      const short8* bl0p = (const short8*)(WGlo + ((tt << 1) << 9)) + lane;
      const short8* bh1p = (const short8*)(WGhi + (((tt << 1) + 1) << 9)) + lane;
      const short8* bl1p = (const short8*)(WGlo + (((tt << 1) + 1) << 9)) + lane;
      short8 bh0 = *bh0p, bl0 = *bl0p, bh1 = *bh1p, bl1 = *bl1p;
      acc[tt] = MFMA16(Gh0, bh0, acc[tt], 0, 0, 0);
      acc[tt] = MFMA16(Gh0, bl0, acc[tt], 0, 0, 0);
      acc[tt] = MFMA16(Gl0, bh0, acc[tt], 0, 0, 0);
      acc[tt] = MFMA16(Gh1, bh1, acc[tt], 0, 0, 0);
      acc[tt] = MFMA16(Gh1, bl1, acc[tt], 0, 0, 0);
      acc[tt] = MFMA16(Gl1, bh1, acc[tt], 0, 0, 0);
    }
    if (t > 0) {
#pragma unroll
      for (int tt = 12; tt < 24; ++tt) {
        const short8* bh0p = (const short8*)(WGhi + ((tt << 1) << 9)) + lane;
        const short8* bl0p = (const short8*)(WGlo + ((tt << 1) << 9)) + lane;
        const short8* bh1p = (const short8*)(WGhi + (((tt << 1) + 1) << 9)) + lane;
        const short8* bl1p = (const short8*)(WGlo + (((tt << 1) + 1) << 9)) + lane;
        short8 bh0 = *bh0p, bl0 = *bl0p, bh1 = *bh1p, bl1 = *bl1p;
        acc[tt] = MFMA16(Ph0, bh0, acc[tt], 0, 0, 0);
        acc[tt] = MFMA16(Ph0, bl0, acc[tt], 0, 0, 0);
        acc[tt] = MFMA16(Pl0, bh0, acc[tt], 0, 0, 0);
        acc[tt] = MFMA16(Ph1, bh1, acc[tt], 0, 0, 0);
        acc[tt] = MFMA16(Ph1, bl1, acc[tt], 0, 0, 0);
        acc[tt] = MFMA16(Pl1, bh1, acc[tt], 0, 0, 0);
      }
    }
    // epilogue: own-cell hv read, gate math, own-cell cbuf write
#pragma unroll
    for (int ct = 0; ct < 4; ++ct) {
      int c = (ct << 4) + nl;
#pragma unroll
      for (int reg = 0; reg < 4; ++reg) {
        float hv = (t > 0) ? cbuf[(rbase + reg) * CST + c] : 0.f;
        float rg = sigf(acc[ct][reg]      + acc[12 + ct][reg]);
        float zg = sigf(acc[4 + ct][reg]  + acc[16 + ct][reg]);
        float ng = tanhfast(acc[8 + ct][reg] + rg * acc[20 + ct][reg]);
        cbuf[(rbase + reg) * CST + c] = (1.f - zg) * ng + zg * hv;
      }
    }
    __syncthreads();
    float* hout = hout_all + (((size_t)t * Mm + m0) << 6);
#pragma unroll
    for (int i = 0; i < 4; ++i) {
      int idx = (i << 10) + (tid << 2);
      int row = idx >> 6, col = idx & 63;
      *(float4*)(hout + (row << 6) + col) = *(float4*)&cbuf[row * CST + col];
    }
    // next t's staging (ghi) + P-frag reads (cbuf) are safe: all waves passed
    // the sync above, so epilogue writes are complete; stores only read cbuf.
    __syncthreads();
  }
}

// ---------------------------------------------------------------------------
__global__ __launch_bounds__(256) void k_heads(
    const float* __restrict__ Xb,
    const float* __restrict__ oW1, const float* __restrict__ ob1,
    const float* __restrict__ oW2, const float* __restrict__ ob2,
    const float* __restrict__ dW1, const float* __restrict__ db1,
    const float* __restrict__ dW2, const float* __restrict__ db2,
    float* __restrict__ out) {
  __shared__ float w1o[Hh * HB2], w1d[Hh * HB2];
  __shared__ float w2o[HB2], w2d[HB2], b1o[HB2], b1d[HB2];
  int tid = threadIdx.x;
  for (int idx = tid; idx < Hh * HB2; idx += 256) { w1o[idx] = oW1[idx]; w1d[idx] = dW1[idx]; }
  if (tid < HB2) { w2o[tid] = oW2[tid]; w2d[tid] = dW2[tid]; b1o[tid] = ob1[tid]; b1d[tid] = db1[tid]; }
  __syncthreads();
  int r = blockIdx.x * 256 + tid;
  int b = r >> 11, n = r & (Nn - 1);
  const float* xrow = Xb + (((size_t)b * Ss + (Ss - 1)) * Nn + n) * Hh;
  float x[Hh];
  const float4* xp = (const float4*)xrow;
#pragma unroll
  for (int q = 0; q < Hh / 4; ++q) {
    float4 v = xp[q];
    x[4*q] = v.x; x[4*q+1] = v.y; x[4*q+2] = v.z; x[4*q+3] = v.w;
  }
  float acco = ob2[0], accd = db2[0];
  for (int j = 0; j < HB2; ++j) {
    float ho = b1o[j], hd = b1d[j];
#pragma unroll
    for (int k = 0; k < Hh; ++k) {
      ho += x[k] * w1o[k * HB2 + j];
      hd += x[k] * w1d[k * HB2 + j];
    }
    acco += fmaxf(ho, 0.f) * w2o[j];
    accd += fmaxf(hd, 0.f) * w2d[j];
  }
  out[r] = acco;
  out[Bb * Nn + r] = accd;
}

// ---------------------------------------------------------------------------
extern "C" void kernel_launch(void* const* d_in, const int* in_sizes, int n_in,
                              void* d_out, int out_size, void* d_ws, size_t ws_size,
                              hipStream_t stream) {
  const float* x   = (const float*)d_in[0];
  const int*   ei  = (const int*)d_in[1];
  const float* ea  = (const float*)d_in[2];
  const float* Wp  = (const float*)d_in[3];
  const float* bp  = (const float*)d_in[4];
  const float* Wl  = (const float*)d_in[5];
  const float* bl  = (const float*)d_in[6];
  const float* Wr  = (const float*)d_in[7];
  const float* br  = (const float*)d_in[8];
  const float* We  = (const float*)d_in[9];
  const float* att = (const float*)d_in[10];
  const float* gb  = (const float*)d_in[11];
  const float* Wih = (const float*)d_in[12];
  const float* Whh = (const float*)d_in[13];
  const float* bih = (const float*)d_in[14];
  const float* bhh = (const float*)d_in[15];
  const float* oW1 = (const float*)d_in[16];
  const float* ob1 = (const float*)d_in[17];
  const float* oW2 = (const float*)d_in[18];
  const float* ob2 = (const float*)d_in[19];
  const float* dW1 = (const float*)d_in[20];
  const float* db1 = (const float*)d_in[21];
  const float* dW2 = (const float*)d_in[22];
  const float* db2 = (const float*)d_in[23];
  float* out = (float*)d_out;

  // workspace layout
  float* f    = (float*)d_ws;
  float* Xb   = f;                          // RTOT*64
  float* XLb  = Xb  + (size_t)RTOT * Hh;
  float* XRb  = XLb + (size_t)RTOT * Hh;    // hg after k_gat
  float* EPc  = XRb + (size_t)RTOT * Hh;    // 2 * E2c * 64 (CSR order, both layers)
  unsigned short* WXhi = (unsigned short*)(EPc + (size_t)2 * E2c * Hh); // 16384
  unsigned short* WXlo = WXhi + 16384;
  unsigned short* WGhi = WXlo + 16384;      // 49152
  unsigned short* WGlo = WGhi + 49152;
  float* cntF = (float*)(WGlo + 49152);     // 2048
  float* loopA = cntF + Nn;                 // 2048*8
  int*   fillI = (int*)(loopA + Nn * EFf);  // 2048
  int*   offs  = fillI + Nn;                // 2049 (+pad)
  int*   posOf = offs + 2052;               // 18432
  int*   srcA  = posOf + E2c;               // 18432

  hipMemsetAsync(cntF, 0, (size_t)(Nn + Nn * EFf + Nn) * 4, stream);

  k_loop_accum<<<dim3(Ee * EFf / 256), 256, 0, stream>>>(ei, ea, cntF, loopA);
  k_scan<<<1, 256, 0, stream>>>(cntF, offs);
  k_scatter<<<dim3((E2c + 255) / 256), 256, 0, stream>>>(ei, offs, fillI, posOf, srcA);
  k_wprep<<<dim3(256), 256, 0, stream>>>(Wl, Wr, Wih, Whh, WXhi, WXlo, WGhi, WGlo);

  // X = x @ Wp + bp
  k_proj<<<dim3(RTOT / 512, 4), 256, 0, stream>>>(x, Wp, bp, Xb);

  // ep for both layers (division by cnt folded in)
  k_ep<<<dim3(E2c * Hh / 256, 2), 256, 0, stream>>>(ea, loopA, We, posOf, cntF, EPc);

  for (int l = 0; l < 2; ++l) {
    k_xlr_mm<<<dim3(RTOT / 64), 256, 0, stream>>>(
        Xb, WXhi + (size_t)l * 8192, WXlo + (size_t)l * 8192,
        bl + (size_t)l * Hh, br + (size_t)l * Hh, XLb, XRb);
    k_gat<<<dim3(Nn, 8), 256, 0, stream>>>(
        XLb, XRb, EPc + (size_t)l * E2c * Hh, offs, srcA,
        att + (size_t)l * Hh, gb + (size_t)l * Hh);
    k_gru_layer<<<dim3(Mm / 64), 256, 0, stream>>>(
        XRb, WGhi + (size_t)l * 24576, WGlo + (size_t)l * 24576,
        bih + (size_t)l * 192, bhh + (size_t)l * 192, Xb);
  }

  k_heads<<<dim3(Bb * Nn / 256), 256, 0, stream>>>(
      Xb, oW1, ob1, oW2, ob2, dW1, db1, dW2, db2, out);
}

// Round 16
// 479.312 us; speedup vs baseline: 1.2032x; 1.2032x over previous
//
#include <hip/hip_runtime.h>
#include <math.h>

#define Bb   4
#define Ss   16
#define Nn   2048
#define Ff   32
#define Ee   16384
#define EFf  8
#define Hh   64
#define HB2  32
#define E2c  (Ee + Nn)          // 18432
#define RTOT (Bb*Ss*Nn)         // 131072 (64 graphs x 2048)
#define Mm   (Ss*Nn)            // 32768
#define CST  68                 // cbuf row stride

typedef __attribute__((ext_vector_type(8))) short short8;
typedef __attribute__((ext_vector_type(4))) float f32x4;
#define MFMA16 __builtin_amdgcn_mfma_f32_16x16x32_bf16

__device__ __forceinline__ float sigf(float x) { return 1.f / (1.f + __expf(-x)); }
__device__ __forceinline__ float tanhfast(float x) { return 2.f / (1.f + __expf(-2.f * x)) - 1.f; }

__device__ __forceinline__ void split_bf16(float x, unsigned short& h, unsigned short& l) {
  unsigned u = __float_as_uint(x);
  unsigned r = (u + 0x7FFFu + ((u >> 16) & 1u)) >> 16;
  h = (unsigned short)r;
  float rest = x - __uint_as_float(r << 16);
  unsigned u2 = __float_as_uint(rest);
  l = (unsigned short)((u2 + 0x7FFFu + ((u2 >> 16) & 1u)) >> 16);
}

template <int PAT>
__device__ __forceinline__ float xorf(float v) {
  return __int_as_float(__builtin_amdgcn_ds_swizzle(__float_as_int(v), PAT));
}
__device__ __forceinline__ float red8(float v) {
  int x = __builtin_amdgcn_update_dpp(0, __float_as_int(v), 0x128, 0xF, 0xF, true);
  v += __int_as_float(x);
  v += xorf<0x401F>(v);
  v += __shfl_xor(v, 32, 64);
  return v;
}
__device__ __forceinline__ float redlogit(float v) {
  int x;
  x = __builtin_amdgcn_update_dpp(0, __float_as_int(v), 0xB1, 0xF, 0xF, true);
  v += __int_as_float(x);
  x = __builtin_amdgcn_update_dpp(0, __float_as_int(v), 0x4E, 0xF, 0xF, true);
  v += __int_as_float(x);
  v += xorf<0x101F>(v);
  return v;
}

// ---------------------------------------------------------------------------
__global__ __launch_bounds__(256) void k_loop_accum(
    const int* __restrict__ ei, const float* __restrict__ ea,
    float* __restrict__ cntF, float* __restrict__ loopA) {
  int idx = blockIdx.x * 256 + threadIdx.x;
  int e = idx >> 3, j = idx & 7;
  int d = ei[Ee + e];
  atomicAdd(&loopA[d * EFf + j], ea[idx]);
  if (j == 0) atomicAdd(&cntF[d], 1.0f);
}

// ---------------------------------------------------------------------------
__global__ __launch_bounds__(256) void k_scan(
    const float* __restrict__ cntF, int* __restrict__ offs) {
  __shared__ int partial[256];
  int tid = threadIdx.x;
  int base = tid * 8;
  int vals[8];
  int s = 0;
  for (int i = 0; i < 8; ++i) {
    int c = (int)cntF[base + i] + 1;
    vals[i] = c;
    s += c;
  }
  partial[tid] = s;
  __syncthreads();
  for (int off = 1; off < 256; off <<= 1) {
    int v = partial[tid];
    int add = (tid >= off) ? partial[tid - off] : 0;
    __syncthreads();
    partial[tid] = v + add;
    __syncthreads();
  }
  int run = (tid == 0) ? 0 : partial[tid - 1];
  for (int i = 0; i < 8; ++i) {
    offs[base + i] = run;
    run += vals[i];
  }
  if (tid == 255) offs[Nn] = run;
}

__global__ __launch_bounds__(256) void k_scatter(
    const int* __restrict__ ei, const int* __restrict__ offs,
    int* __restrict__ fillI, int* __restrict__ posOf, int* __restrict__ srcA) {
  int e = blockIdx.x * 256 + threadIdx.x;
  if (e >= E2c) return;
  int d = (e < Ee) ? ei[Ee + e] : (e - Ee);
  int s = (e < Ee) ? ei[e]      : (e - Ee);
  int pos = offs[d] + atomicAdd(&fillI[d], 1);
  posOf[e] = pos;
  srcA[pos] = s;
}

// ---------------------------------------------------------------------------
// Pre-split + pre-swizzle weights into MFMA B-fragment order (R9 layout).
// ---------------------------------------------------------------------------
__global__ __launch_bounds__(256) void k_wprep(
    const float* __restrict__ Wl, const float* __restrict__ Wr,
    const float* __restrict__ Wih, const float* __restrict__ Whh,
    unsigned short* __restrict__ WXhi, unsigned short* __restrict__ WXlo,
    unsigned short* __restrict__ WGhi, unsigned short* __restrict__ WGlo) {
  int idx = blockIdx.x * 256 + threadIdx.x;   // 65536 total
  if (idx < 16384) {
    int j = idx & 7, lane = (idx >> 3) & 63, kh = (idx >> 9) & 1;
    int t = (idx >> 10) & 7, l = idx >> 13;
    int n = t * 16 + (lane & 15);
    int k = kh * 32 + ((lane >> 4) << 3) + j;
    const float* W = (n < 64) ? (Wl + (size_t)l * 4096) : (Wr + (size_t)l * 4096);
    float v = W[k * 64 + (n & 63)];
    unsigned short h, lo;
    split_bf16(v, h, lo);
    WXhi[idx] = h; WXlo[idx] = lo;
  } else {
    int i2 = idx - 16384;                     // < 49152
    int j = i2 & 7, lane = (i2 >> 3) & 63, kh = (i2 >> 9) & 1;
    int t = (i2 >> 10) % 24, l = i2 / 24576;
    int n = t * 16 + (lane & 15);
    int k = kh * 32 + ((lane >> 4) << 3) + j;
    int g = n >> 6, c = n & 63;
    const float* W = (g < 3) ? (Wih + (size_t)l * 12288 + (size_t)(g * 64 + c) * 64)
                             : (Whh + (size_t)l * 12288 + (size_t)((g - 3) * 64 + c) * 64);
    float v = W[k];
    unsigned short h, lo;
    split_bf16(v, h, lo);
    WGhi[i2] = h; WGlo[i2] = lo;
  }
}

// ---------------------------------------------------------------------------
// ep for BOTH layers; self-loop mean division folded in. blockIdx.y = layer.
// ---------------------------------------------------------------------------
__global__ __launch_bounds__(256) void k_ep(
    const float* __restrict__ ea, const float* __restrict__ loopA,
    const float* __restrict__ We, const int* __restrict__ posOf,
    const float* __restrict__ cntF, float* __restrict__ EPc) {
  __shared__ float wlds[EFf * Hh];
  int tid = threadIdx.x;
  int l = blockIdx.y;
  const float* Wel = We + (size_t)l * EFf * Hh;
  if (tid < EFf * Hh) wlds[tid] = Wel[tid];
  if (tid + 256 < EFf * Hh) wlds[tid + 256] = Wel[tid + 256];
  __syncthreads();
  int idx = blockIdx.x * 256 + tid;
  int e = idx >> 6, j = idx & 63;
  const float* a = (e < Ee) ? (ea + (size_t)e * EFf) : (loopA + (size_t)(e - Ee) * EFf);
  float acc = 0.f;
#pragma unroll
  for (int k = 0; k < EFf; ++k) acc += a[k] * wlds[k * Hh + j];
  if (e >= Ee) acc /= fmaxf(cntF[e - Ee], 1.0f);
  EPc[(size_t)l * E2c * Hh + (((size_t)posOf[e]) << 6) + j] = acc;
}

// ---------------------------------------------------------------------------
// proj (R5 version): thread = 2 rows x 16 cols. grid (RTOT/512, 4)
// ---------------------------------------------------------------------------
__global__ __launch_bounds__(256) void k_proj(
    const float* __restrict__ X, const float* __restrict__ Wp,
    const float* __restrict__ bp, float* __restrict__ Out) {
  __shared__ float w[32 * 16];
  int tid = threadIdx.x;
  int j0 = blockIdx.y << 4;
  for (int idx = tid; idx < 32 * 16; idx += 256)
    w[idx] = Wp[((idx >> 4) << 6) + j0 + (idx & 15)];
  __syncthreads();
  int r0 = (blockIdx.x << 9) + tid;
  float acc[2][16];
#pragma unroll
  for (int jj = 0; jj < 16; ++jj) { float b = bp[j0 + jj]; acc[0][jj] = b; acc[1][jj] = b; }
  const float* x0 = X + ((size_t)r0 << 5);
  const float* x1 = x0 + (256 << 5);
  for (int kc = 0; kc < 8; ++kc) {
    float4 a0 = *(const float4*)(x0 + 4 * kc);
    float4 a1 = *(const float4*)(x1 + 4 * kc);
    float a0a[4] = {a0.x, a0.y, a0.z, a0.w};
    float a1a[4] = {a1.x, a1.y, a1.z, a1.w};
#pragma unroll
    for (int q = 0; q < 4; ++q) {
      const float4* wp4 = (const float4*)(w + ((4 * kc + q) << 4));
#pragma unroll
      for (int q4 = 0; q4 < 4; ++q4) {
        float4 wv = wp4[q4];
        acc[0][4*q4+0] = fmaf(a0a[q], wv.x, acc[0][4*q4+0]);
        acc[0][4*q4+1] = fmaf(a0a[q], wv.y, acc[0][4*q4+1]);
        acc[0][4*q4+2] = fmaf(a0a[q], wv.z, acc[0][4*q4+2]);
        acc[0][4*q4+3] = fmaf(a0a[q], wv.w, acc[0][4*q4+3]);
        acc[1][4*q4+0] = fmaf(a1a[q], wv.x, acc[1][4*q4+0]);
        acc[1][4*q4+1] = fmaf(a1a[q], wv.y, acc[1][4*q4+1]);
        acc[1][4*q4+2] = fmaf(a1a[q], wv.z, acc[1][4*q4+2]);
        acc[1][4*q4+3] = fmaf(a1a[q], wv.w, acc[1][4*q4+3]);
      }
    }
  }
#pragma unroll
  for (int rr = 0; rr < 2; ++rr) {
    float* op = Out + (((size_t)(r0 + 256 * rr)) << 6) + j0;
#pragma unroll
    for (int q4 = 0; q4 < 4; ++q4)
      *(float4*)(op + 4 * q4) = make_float4(acc[rr][4*q4], acc[rr][4*q4+1], acc[rr][4*q4+2], acc[rr][4*q4+3]);
  }
}

// ---------------------------------------------------------------------------
// XL/XR via bf16x3 MFMA (R14, measured good).
// ---------------------------------------------------------------------------
__global__ __launch_bounds__(256) void k_xlr_mm(
    const float* __restrict__ X,
    const unsigned short* __restrict__ WXhi, const unsigned short* __restrict__ WXlo,
    const float* __restrict__ bl_, const float* __restrict__ br_,
    float* __restrict__ XL, float* __restrict__ XR) {
  __shared__ unsigned short ahi[4096], alo[4096];
  __shared__ float cbuf[64 * CST];
  int tid = threadIdx.x, lane = tid & 63, wv = tid >> 6;
  size_t m0 = (size_t)blockIdx.x << 6;
#pragma unroll
  for (int it = 0; it < 2; ++it) {
    int task = (it << 8) + tid;
    int row = task >> 3, cOct = task & 7;
    const float* src = X + ((m0 + row) << 6) + (cOct << 3);
    float4 a = *(const float4*)src;
    float4 b = *(const float4*)(src + 4);
    float va[8] = {a.x, a.y, a.z, a.w, b.x, b.y, b.z, b.w};
    short8 hv, lv;
#pragma unroll
    for (int j = 0; j < 8; ++j) {
      unsigned short hs, ls;
      split_bf16(va[j], hs, ls);
      hv[j] = (short)hs; lv[j] = (short)ls;
    }
    int f = ((cOct >> 2) * 4 + (row >> 4)) * 64 + ((cOct & 3) << 4) + (row & 15);
    *(short8*)&ahi[f << 3] = hv;
    *(short8*)&alo[f << 3] = lv;
  }
  __syncthreads();
  short8 Ah0 = *(const short8*)&ahi[((0 + wv) << 6 | lane) << 3];
  short8 Al0 = *(const short8*)&alo[((0 + wv) << 6 | lane) << 3];
  short8 Ah1 = *(const short8*)&ahi[((4 + wv) << 6 | lane) << 3];
  short8 Al1 = *(const short8*)&alo[((4 + wv) << 6 | lane) << 3];
  int nl = lane & 15;
  f32x4 acc[8];
#pragma unroll
  for (int t = 0; t < 8; ++t) {
    int n = t * 16 + nl;
    float b = (n < 64) ? bl_[n] : br_[n - 64];
    acc[t] = (f32x4){b, b, b, b};
  }
#pragma unroll
  for (int t = 0; t < 8; ++t) {
    const short8* bh0p = (const short8*)(WXhi + ((t << 1) << 9)) + lane;
    const short8* bl0p = (const short8*)(WXlo + ((t << 1) << 9)) + lane;
    const short8* bh1p = (const short8*)(WXhi + (((t << 1) + 1) << 9)) + lane;
    const short8* bl1p = (const short8*)(WXlo + (((t << 1) + 1) << 9)) + lane;
    short8 bh0 = *bh0p, bl0 = *bl0p, bh1 = *bh1p, bl1 = *bl1p;
    acc[t] = MFMA16(Ah0, bh0, acc[t], 0, 0, 0);
    acc[t] = MFMA16(Ah0, bl0, acc[t], 0, 0, 0);
    acc[t] = MFMA16(Al0, bh0, acc[t], 0, 0, 0);
    acc[t] = MFMA16(Ah1, bh1, acc[t], 0, 0, 0);
    acc[t] = MFMA16(Ah1, bl1, acc[t], 0, 0, 0);
    acc[t] = MFMA16(Al1, bh1, acc[t], 0, 0, 0);
  }
  int rbase = (wv << 4) + ((lane >> 4) << 2);
#pragma unroll
  for (int half = 0; half < 2; ++half) {
    __syncthreads();
#pragma unroll
    for (int tt = 0; tt < 4; ++tt) {
      int t = (half << 2) + tt;
#pragma unroll
      for (int reg = 0; reg < 4; ++reg)
        cbuf[(rbase + reg) * CST + (tt << 4) + nl] = acc[t][reg];
    }
    __syncthreads();
    float* dst = half ? XR : XL;
#pragma unroll
    for (int i = 0; i < 4; ++i) {
      int idx = (i << 10) + (tid << 2);
      int row = idx >> 6, col = idx & 63;
      *(float4*)(dst + ((m0 + row) << 6) + col) = *(float4*)&cbuf[row * CST + col];
    }
  }
}

// ---------------------------------------------------------------------------
// GATv2 v6 (R15): block = (dst d, graph octet q). Each wave handles graphs
// q*8+wv and q*8+wv+4. L2 window = 8 XL slabs (4 MB). 16384 blocks.
// ---------------------------------------------------------------------------
__global__ __launch_bounds__(256) void k_gat(
    const float* __restrict__ XL, float* __restrict__ XR_HG,
    const float* __restrict__ EPc, const int* __restrict__ offs,
    const int* __restrict__ srcA,
    const float* __restrict__ att, const float* __restrict__ gbl) {
  int d = blockIdx.x;
  int q = blockIdx.y;
  int tid = threadIdx.x;
  int wv = tid >> 6, lane = tid & 63;
  int eSub = lane >> 3, hOct = lane & 7;
  int hb = hOct << 3;
  float at[8], gv[8];
  {
    float4 a0 = *(const float4*)(att + hb);
    float4 a1 = *(const float4*)(att + hb + 4);
    float4 g0v = *(const float4*)(gbl + hb);
    float4 g1v = *(const float4*)(gbl + hb + 4);
    at[0]=a0.x; at[1]=a0.y; at[2]=a0.z; at[3]=a0.w;
    at[4]=a1.x; at[5]=a1.y; at[6]=a1.z; at[7]=a1.w;
    gv[0]=g0v.x; gv[1]=g0v.y; gv[2]=g0v.z; gv[3]=g0v.w;
    gv[4]=g1v.x; gv[5]=g1v.y; gv[6]=g1v.z; gv[7]=g1v.w;
  }
  int p0 = offs[d], p1 = offs[d + 1];
  int nE = p1 - p0;
  int nCh = (nE + 7) >> 3;
  int g0 = (q << 3) + wv;
  int g1 = g0 + 4;
  size_t rowA = ((size_t)(g0 * Nn + d)) << 6;
  size_t rowB = ((size_t)(g1 * Nn + d)) << 6;
  float xrA[8], xrB[8];
  {
    float4 a = *(const float4*)(XR_HG + rowA + hb);
    float4 b = *(const float4*)(XR_HG + rowA + hb + 4);
    float4 c = *(const float4*)(XR_HG + rowB + hb);
    float4 e = *(const float4*)(XR_HG + rowB + hb + 4);
    xrA[0]=a.x; xrA[1]=a.y; xrA[2]=a.z; xrA[3]=a.w; xrA[4]=b.x; xrA[5]=b.y; xrA[6]=b.z; xrA[7]=b.w;
    xrB[0]=c.x; xrB[1]=c.y; xrB[2]=c.z; xrB[3]=c.w; xrB[4]=e.x; xrB[5]=e.y; xrB[6]=e.z; xrB[7]=e.w;
  }
  const float* XA = XL + (((size_t)g0 * Nn) << 6);
  const float* XB = XL + (((size_t)g1 * Nn) << 6);
  float SsA = 0.f, SsB = 0.f;
  float accA[8], accB[8];
#pragma unroll
  for (int j = 0; j < 8; ++j) { accA[j] = 0.f; accB[j] = 0.f; }
  for (int c = 0; c < nCh; ++c) {
    int p = (c << 3) + eSub;
    int pc = p < nE ? p : nE - 1;
    int s = srcA[p0 + pc];
    const float* epp = EPc + (((size_t)(p0 + pc)) << 6) + hb;
    float4 e0 = *(const float4*)epp;
    float4 e1 = *(const float4*)(epp + 4);
    float ep[8] = {e0.x, e0.y, e0.z, e0.w, e1.x, e1.y, e1.z, e1.w};
    const float* xap = XA + ((size_t)s << 6) + hb;
    const float* xbp = XB + ((size_t)s << 6) + hb;
    float4 xa0 = *(const float4*)xap, xa1 = *(const float4*)(xap + 4);
    float4 xb0 = *(const float4*)xbp, xb1 = *(const float4*)(xbp + 4);
    float xA[8] = {xa0.x, xa0.y, xa0.z, xa0.w, xa1.x, xa1.y, xa1.z, xa1.w};
    float xB[8] = {xb0.x, xb0.y, xb0.z, xb0.w, xb1.x, xb1.y, xb1.z, xb1.w};
    float vA = 0.f, vB = 0.f;
#pragma unroll
    for (int j = 0; j < 8; ++j) {
      float mA = xA[j] + xrA[j] + ep[j];
      mA = fmaxf(mA, 0.2f * mA);
      vA = fmaf(mA, at[j], vA);
      float mB = xB[j] + xrB[j] + ep[j];
      mB = fmaxf(mB, 0.2f * mB);
      vB = fmaf(mB, at[j], vB);
    }
    vA = redlogit(vA);
    vB = redlogit(vB);
    float wA = (p < nE) ? __expf(vA) : 0.f;
    float wB = (p < nE) ? __expf(vB) : 0.f;
    SsA += wA; SsB += wB;
#pragma unroll
    for (int j = 0; j < 8; ++j) {
      accA[j] = fmaf(wA, xA[j], accA[j]);
      accB[j] = fmaf(wB, xB[j], accB[j]);
    }
  }
  SsA = red8(SsA); SsB = red8(SsB);
#pragma unroll
  for (int j = 0; j < 8; ++j) { accA[j] = red8(accA[j]); accB[j] = red8(accB[j]); }
  if (eSub == 0) {
    float invA = 1.f / SsA, invB = 1.f / SsB;
    float* opA = XR_HG + rowA + hb;
    float* opB = XR_HG + rowB + hb;
    *(float4*)(opA)     = make_float4(fmaf(accA[0], invA, gv[0]), fmaf(accA[1], invA, gv[1]),
                                      fmaf(accA[2], invA, gv[2]), fmaf(accA[3], invA, gv[3]));
    *(float4*)(opA + 4) = make_float4(fmaf(accA[4], invA, gv[4]), fmaf(accA[5], invA, gv[5]),
                                      fmaf(accA[6], invA, gv[6]), fmaf(accA[7], invA, gv[7]));
    *(float4*)(opB)     = make_float4(fmaf(accB[0], invB, gv[0]), fmaf(accB[1], invB, gv[1]),
                                      fmaf(accB[2], invB, gv[2]), fmaf(accB[3], invB, gv[3]));
    *(float4*)(opB + 4) = make_float4(fmaf(accB[4], invB, gv[4]), fmaf(accB[5], invB, gv[5]),
                                      fmaf(accB[6], invB, gv[6]), fmaf(accB[7], invB, gv[7]));
  }
}

// ---------------------------------------------------------------------------
// Per-t fused GRU via bf16x3 MFMA (R14, measured good): dedicated padded
// LDS epilogue buffer, coalesced h stores.
// ---------------------------------------------------------------------------
template <int HASP>
__global__ __launch_bounds__(256) void k_gru_mm(
    const float* __restrict__ hg, const float* __restrict__ hp,
    const unsigned short* __restrict__ WGhi, const unsigned short* __restrict__ WGlo,
    const float* __restrict__ bih, const float* __restrict__ bhh,
    float* __restrict__ hout) {
  __shared__ unsigned short ghi[4096], glo[4096], phi[4096], plo[4096];
  __shared__ float cbuf[64 * CST];
  int tid = threadIdx.x, lane = tid & 63, wv = tid >> 6;
  size_t m0 = (size_t)blockIdx.x << 6;
#pragma unroll
  for (int it = 0; it < 2; ++it) {
    int task = (it << 8) + tid;
    int row = task >> 3, cOct = task & 7;
    const float* srcg = hg + ((m0 + row) << 6) + (cOct << 3);
    float4 a = *(const float4*)srcg;
    float4 b = *(const float4*)(srcg + 4);
    float va[8] = {a.x, a.y, a.z, a.w, b.x, b.y, b.z, b.w};
    short8 hv, lv;
#pragma unroll
    for (int j = 0; j < 8; ++j) {
      unsigned short hs, ls;
      split_bf16(va[j], hs, ls);
      hv[j] = (short)hs; lv[j] = (short)ls;
    }
    int f = ((cOct >> 2) * 4 + (row >> 4)) * 64 + ((cOct & 3) << 4) + (row & 15);
    *(short8*)&ghi[f << 3] = hv;
    *(short8*)&glo[f << 3] = lv;
    if (HASP) {
      const float* srcp = hp + ((m0 + row) << 6) + (cOct << 3);
      float4 c = *(const float4*)srcp;
      float4 e = *(const float4*)(srcp + 4);
      float vp[8] = {c.x, c.y, c.z, c.w, e.x, e.y, e.z, e.w};
#pragma unroll
      for (int j = 0; j < 8; ++j) {
        unsigned short hs, ls;
        split_bf16(vp[j], hs, ls);
        hv[j] = (short)hs; lv[j] = (short)ls;
      }
      *(short8*)&phi[f << 3] = hv;
      *(short8*)&plo[f << 3] = lv;
    }
  }
  __syncthreads();
  short8 Gh0 = *(const short8*)&ghi[((0 + wv) << 6 | lane) << 3];
  short8 Gl0 = *(const short8*)&glo[((0 + wv) << 6 | lane) << 3];
  short8 Gh1 = *(const short8*)&ghi[((4 + wv) << 6 | lane) << 3];
  short8 Gl1 = *(const short8*)&glo[((4 + wv) << 6 | lane) << 3];
  short8 Ph0, Pl0, Ph1, Pl1;
  if (HASP) {
    Ph0 = *(const short8*)&phi[((0 + wv) << 6 | lane) << 3];
    Pl0 = *(const short8*)&plo[((0 + wv) << 6 | lane) << 3];
    Ph1 = *(const short8*)&phi[((4 + wv) << 6 | lane) << 3];
    Pl1 = *(const short8*)&plo[((4 + wv) << 6 | lane) << 3];
  }
  int nl = lane & 15;
  f32x4 acc[24];
#pragma unroll
  for (int t = 0; t < 24; ++t) {
    int g = t >> 2;
    int c = ((t & 3) << 4) + nl;
    float b = (g < 3) ? bih[(g << 6) + c] : bhh[((g - 3) << 6) + c];
    acc[t] = (f32x4){b, b, b, b};
  }
#pragma unroll
  for (int t = 0; t < 12; ++t) {
    const short8* bh0p = (const short8*)(WGhi + ((t << 1) << 9)) + lane;
    const short8* bl0p = (const short8*)(WGlo + ((t << 1) << 9)) + lane;
    const short8* bh1p = (const short8*)(WGhi + (((t << 1) + 1) << 9)) + lane;
    const short8* bl1p = (const short8*)(WGlo + (((t << 1) + 1) << 9)) + lane;
    short8 bh0 = *bh0p, bl0 = *bl0p, bh1 = *bh1p, bl1 = *bl1p;
    acc[t] = MFMA16(Gh0, bh0, acc[t], 0, 0, 0);
    acc[t] = MFMA16(Gh0, bl0, acc[t], 0, 0, 0);
    acc[t] = MFMA16(Gl0, bh0, acc[t], 0, 0, 0);
    acc[t] = MFMA16(Gh1, bh1, acc[t], 0, 0, 0);
    acc[t] = MFMA16(Gh1, bl1, acc[t], 0, 0, 0);
    acc[t] = MFMA16(Gl1, bh1, acc[t], 0, 0, 0);
  }
  if (HASP) {
#pragma unroll
    for (int t = 12; t < 24; ++t) {
      const short8* bh0p = (const short8*)(WGhi + ((t << 1) << 9)) + lane;
      const short8* bl0p = (const short8*)(WGlo + ((t << 1) << 9)) + lane;
      const short8* bh1p = (const short8*)(WGhi + (((t << 1) + 1) << 9)) + lane;
      const short8* bl1p = (const short8*)(WGlo + (((t << 1) + 1) << 9)) + lane;
      short8 bh0 = *bh0p, bl0 = *bl0p, bh1 = *bh1p, bl1 = *bl1p;
      acc[t] = MFMA16(Ph0, bh0, acc[t], 0, 0, 0);
      acc[t] = MFMA16(Ph0, bl0, acc[t], 0, 0, 0);
      acc[t] = MFMA16(Pl0, bh0, acc[t], 0, 0, 0);
      acc[t] = MFMA16(Ph1, bh1, acc[t], 0, 0, 0);
      acc[t] = MFMA16(Ph1, bl1, acc[t], 0, 0, 0);
      acc[t] = MFMA16(Pl1, bh1, acc[t], 0, 0, 0);
    }
  }
  int rbase = (wv << 4) + ((lane >> 4) << 2);
#pragma unroll
  for (int ct = 0; ct < 4; ++ct) {
    int c = (ct << 4) + nl;
#pragma unroll
    for (int reg = 0; reg < 4; ++reg) {
      size_t rowg = m0 + rbase + reg;
      float rg = sigf(acc[ct][reg]      + acc[12 + ct][reg]);
      float zg = sigf(acc[4 + ct][reg]  + acc[16 + ct][reg]);
      float ng = tanhfast(acc[8 + ct][reg] + rg * acc[20 + ct][reg]);
      float hv = HASP ? hp[(rowg << 6) + c] : 0.f;
      cbuf[(rbase + reg) * CST + c] = (1.f - zg) * ng + zg * hv;
    }
  }
  __syncthreads();
#pragma unroll
  for (int i = 0; i < 4; ++i) {
    int idx = (i << 10) + (tid << 2);
    int row = idx >> 6, col = idx & 63;
    *(float4*)(hout + ((m0 + row) << 6) + col) = *(float4*)&cbuf[row * CST + col];
  }
}

// ---------------------------------------------------------------------------
__global__ __launch_bounds__(256) void k_heads(
    const float* __restrict__ Xb,
    const float* __restrict__ oW1, const float* __restrict__ ob1,
    const float* __restrict__ oW2, const float* __restrict__ ob2,
    const float* __restrict__ dW1, const float* __restrict__ db1,
    const float* __restrict__ dW2, const float* __restrict__ db2,
    float* __restrict__ out) {
  __shared__ float w1o[Hh * HB2], w1d[Hh * HB2];
  __shared__ float w2o[HB2], w2d[HB2], b1o[HB2], b1d[HB2];
  int tid = threadIdx.x;
  for (int idx = tid; idx < Hh * HB2; idx += 256) { w1o[idx] = oW1[idx]; w1d[idx] = dW1[idx]; }
  if (tid < HB2) { w2o[tid] = oW2[tid]; w2d[tid] = dW2[tid]; b1o[tid] = ob1[tid]; b1d[tid] = db1[tid]; }
  __syncthreads();
  int r = blockIdx.x * 256 + tid;
  int b = r >> 11, n = r & (Nn - 1);
  const float* xrow = Xb + (((size_t)b * Ss + (Ss - 1)) * Nn + n) * Hh;
  float x[Hh];
  const float4* xp = (const float4*)xrow;
#pragma unroll
  for (int q = 0; q < Hh / 4; ++q) {
    float4 v = xp[q];
    x[4*q] = v.x; x[4*q+1] = v.y; x[4*q+2] = v.z; x[4*q+3] = v.w;
  }
  float acco = ob2[0], accd = db2[0];
  for (int j = 0; j < HB2; ++j) {
    float ho = b1o[j], hd = b1d[j];
#pragma unroll
    for (int k = 0; k < Hh; ++k) {
      ho += x[k] * w1o[k * HB2 + j];
      hd += x[k] * w1d[k * HB2 + j];
    }
    acco += fmaxf(ho, 0.f) * w2o[j];
    accd += fmaxf(hd, 0.f) * w2d[j];
  }
  out[r] = acco;
  out[Bb * Nn + r] = accd;
}

// ---------------------------------------------------------------------------
extern "C" void kernel_launch(void* const* d_in, const int* in_sizes, int n_in,
                              void* d_out, int out_size, void* d_ws, size_t ws_size,
                              hipStream_t stream) {
  const float* x   = (const float*)d_in[0];
  const int*   ei  = (const int*)d_in[1];
  const float* ea  = (const float*)d_in[2];
  const float* Wp  = (const float*)d_in[3];
  const float* bp  = (const float*)d_in[4];
  const float* Wl  = (const float*)d_in[5];
  const float* bl  = (const float*)d_in[6];
  const float* Wr  = (const float*)d_in[7];
  const float* br  = (const float*)d_in[8];
  const float* We  = (const float*)d_in[9];
  const float* att = (const float*)d_in[10];
  const float* gb  = (const float*)d_in[11];
  const float* Wih = (const float*)d_in[12];
  const float* Whh = (const float*)d_in[13];
  const float* bih = (const float*)d_in[14];
  const float* bhh = (const float*)d_in[15];
  const float* oW1 = (const float*)d_in[16];
  const float* ob1 = (const float*)d_in[17];
  const float* oW2 = (const float*)d_in[18];
  const float* ob2 = (const float*)d_in[19];
  const float* dW1 = (const float*)d_in[20];
  const float* db1 = (const float*)d_in[21];
  const float* dW2 = (const float*)d_in[22];
  const float* db2 = (const float*)d_in[23];
  float* out = (float*)d_out;

  // workspace layout
  float* f    = (float*)d_ws;
  float* Xb   = f;                          // RTOT*64
  float* XLb  = Xb  + (size_t)RTOT * Hh;
  float* XRb  = XLb + (size_t)RTOT * Hh;    // hg after k_gat
  float* EPc  = XRb + (size_t)RTOT * Hh;    // 2 * E2c * 64 (CSR order, both layers)
  unsigned short* WXhi = (unsigned short*)(EPc + (size_t)2 * E2c * Hh); // 16384
  unsigned short* WXlo = WXhi + 16384;
  unsigned short* WGhi = WXlo + 16384;      // 49152
  unsigned short* WGlo = WGhi + 49152;
  float* cntF = (float*)(WGlo + 49152);     // 2048
  float* loopA = cntF + Nn;                 // 2048*8
  int*   fillI = (int*)(loopA + Nn * EFf);  // 2048
  int*   offs  = fillI + Nn;                // 2049 (+pad)
  int*   posOf = offs + 2052;               // 18432
  int*   srcA  = posOf + E2c;               // 18432

  hipMemsetAsync(cntF, 0, (size_t)(Nn + Nn * EFf + Nn) * 4, stream);

  k_loop_accum<<<dim3(Ee * EFf / 256), 256, 0, stream>>>(ei, ea, cntF, loopA);
  k_scan<<<1, 256, 0, stream>>>(cntF, offs);
  k_scatter<<<dim3((E2c + 255) / 256), 256, 0, stream>>>(ei, offs, fillI, posOf, srcA);
  k_wprep<<<dim3(256), 256, 0, stream>>>(Wl, Wr, Wih, Whh, WXhi, WXlo, WGhi, WGlo);

  // X = x @ Wp + bp
  k_proj<<<dim3(RTOT / 512, 4), 256, 0, stream>>>(x, Wp, bp, Xb);

  // ep for both layers (division by cnt folded in)
  k_ep<<<dim3(E2c * Hh / 256, 2), 256, 0, stream>>>(ea, loopA, We, posOf, cntF, EPc);

  for (int l = 0; l < 2; ++l) {
    k_xlr_mm<<<dim3(RTOT / 64), 256, 0, stream>>>(
        Xb, WXhi + (size_t)l * 8192, WXlo + (size_t)l * 8192,
        bl + (size_t)l * Hh, br + (size_t)l * Hh, XLb, XRb);
    k_gat<<<dim3(Nn, 8), 256, 0, stream>>>(
        XLb, XRb, EPc + (size_t)l * E2c * Hh, offs, srcA,
        att + (size_t)l * Hh, gb + (size_t)l * Hh);
    const unsigned short* WGh_l = WGhi + (size_t)l * 24576;
    const unsigned short* WGl_l = WGlo + (size_t)l * 24576;
    const float* bih_l = bih + (size_t)l * 192;
    const float* bhh_l = bhh + (size_t)l * 192;
    for (int t = 0; t < Bb; ++t) {
      const float* hg_t = XRb + (size_t)t * Mm * Hh;
      float* h_out = Xb + (size_t)t * Mm * Hh;
      if (t == 0) {
        k_gru_mm<0><<<dim3(Mm / 64), 256, 0, stream>>>(
            hg_t, nullptr, WGh_l, WGl_l, bih_l, bhh_l, h_out);
      } else {
        const float* h_prev = Xb + (size_t)(t - 1) * Mm * Hh;
        k_gru_mm<1><<<dim3(Mm / 64), 256, 0, stream>>>(
            hg_t, h_prev, WGh_l, WGl_l, bih_l, bhh_l, h_out);
      }
    }
  }

  k_heads<<<dim3(Bb * Nn / 256), 256, 0, stream>>>(
      Xb, oW1, ob1, oW2, ob2, dW1, db1, dW2, db2, out);
}

// Round 17
// 425.020 us; speedup vs baseline: 1.3569x; 1.1277x over previous
//
#include <hip/hip_runtime.h>
#include <math.h>

#define Bb   4
#define Ss   16
#define Nn   2048
#define Ff   32
#define Ee   16384
#define EFf  8
#define Hh   64
#define HB2  32
#define E2c  (Ee + Nn)          // 18432
#define RTOT (Bb*Ss*Nn)         // 131072 (64 graphs x 2048)
#define Mm   (Ss*Nn)            // 32768
#define CST  68                 // cbuf row stride

typedef __attribute__((ext_vector_type(8))) short short8;
typedef __attribute__((ext_vector_type(4))) float f32x4;
#define MFMA16 __builtin_amdgcn_mfma_f32_16x16x32_bf16

__device__ __forceinline__ float sigf(float x) { return 1.f / (1.f + __expf(-x)); }
__device__ __forceinline__ float tanhfast(float x) { return 2.f / (1.f + __expf(-2.f * x)) - 1.f; }

__device__ __forceinline__ void split_bf16(float x, unsigned short& h, unsigned short& l) {
  unsigned u = __float_as_uint(x);
  unsigned r = (u + 0x7FFFu + ((u >> 16) & 1u)) >> 16;
  h = (unsigned short)r;
  float rest = x - __uint_as_float(r << 16);
  unsigned u2 = __float_as_uint(rest);
  l = (unsigned short)((u2 + 0x7FFFu + ((u2 >> 16) & 1u)) >> 16);
}

template <int PAT>
__device__ __forceinline__ float xorf(float v) {
  return __int_as_float(__builtin_amdgcn_ds_swizzle(__float_as_int(v), PAT));
}
__device__ __forceinline__ float red8(float v) {
  int x = __builtin_amdgcn_update_dpp(0, __float_as_int(v), 0x128, 0xF, 0xF, true);
  v += __int_as_float(x);
  v += xorf<0x401F>(v);
  v += __shfl_xor(v, 32, 64);
  return v;
}
__device__ __forceinline__ float redlogit(float v) {
  int x;
  x = __builtin_amdgcn_update_dpp(0, __float_as_int(v), 0xB1, 0xF, 0xF, true);
  v += __int_as_float(x);
  x = __builtin_amdgcn_update_dpp(0, __float_as_int(v), 0x4E, 0xF, 0xF, true);
  v += __int_as_float(x);
  v += xorf<0x101F>(v);
  return v;
}

// ---------------------------------------------------------------------------
__global__ __launch_bounds__(256) void k_loop_accum(
    const int* __restrict__ ei, const float* __restrict__ ea,
    float* __restrict__ cntF, float* __restrict__ loopA) {
  int idx = blockIdx.x * 256 + threadIdx.x;
  int e = idx >> 3, j = idx & 7;
  int d = ei[Ee + e];
  atomicAdd(&loopA[d * EFf + j], ea[idx]);
  if (j == 0) atomicAdd(&cntF[d], 1.0f);
}

// ---------------------------------------------------------------------------
__global__ __launch_bounds__(256) void k_scan(
    const float* __restrict__ cntF, int* __restrict__ offs) {
  __shared__ int partial[256];
  int tid = threadIdx.x;
  int base = tid * 8;
  int vals[8];
  int s = 0;
  for (int i = 0; i < 8; ++i) {
    int c = (int)cntF[base + i] + 1;
    vals[i] = c;
    s += c;
  }
  partial[tid] = s;
  __syncthreads();
  for (int off = 1; off < 256; off <<= 1) {
    int v = partial[tid];
    int add = (tid >= off) ? partial[tid - off] : 0;
    __syncthreads();
    partial[tid] = v + add;
    __syncthreads();
  }
  int run = (tid == 0) ? 0 : partial[tid - 1];
  for (int i = 0; i < 8; ++i) {
    offs[base + i] = run;
    run += vals[i];
  }
  if (tid == 255) offs[Nn] = run;
}

__global__ __launch_bounds__(256) void k_scatter(
    const int* __restrict__ ei, const int* __restrict__ offs,
    int* __restrict__ fillI, int* __restrict__ posOf, int* __restrict__ srcA) {
  int e = blockIdx.x * 256 + threadIdx.x;
  if (e >= E2c) return;
  int d = (e < Ee) ? ei[Ee + e] : (e - Ee);
  int s = (e < Ee) ? ei[e]      : (e - Ee);
  int pos = offs[d] + atomicAdd(&fillI[d], 1);
  posOf[e] = pos;
  srcA[pos] = s;
}

// ---------------------------------------------------------------------------
// Pre-split + pre-swizzle weights into MFMA B-fragment order (R9 layout).
// ---------------------------------------------------------------------------
__global__ __launch_bounds__(256) void k_wprep(
    const float* __restrict__ Wl, const float* __restrict__ Wr,
    const float* __restrict__ Wih, const float* __restrict__ Whh,
    unsigned short* __restrict__ WXhi, unsigned short* __restrict__ WXlo,
    unsigned short* __restrict__ WGhi, unsigned short* __restrict__ WGlo) {
  int idx = blockIdx.x * 256 + threadIdx.x;   // 65536 total
  if (idx < 16384) {
    int j = idx & 7, lane = (idx >> 3) & 63, kh = (idx >> 9) & 1;
    int t = (idx >> 10) & 7, l = idx >> 13;
    int n = t * 16 + (lane & 15);
    int k = kh * 32 + ((lane >> 4) << 3) + j;
    const float* W = (n < 64) ? (Wl + (size_t)l * 4096) : (Wr + (size_t)l * 4096);
    float v = W[k * 64 + (n & 63)];
    unsigned short h, lo;
    split_bf16(v, h, lo);
    WXhi[idx] = h; WXlo[idx] = lo;
  } else {
    int i2 = idx - 16384;                     // < 49152
    int j = i2 & 7, lane = (i2 >> 3) & 63, kh = (i2 >> 9) & 1;
    int t = (i2 >> 10) % 24, l = i2 / 24576;
    int n = t * 16 + (lane & 15);
    int k = kh * 32 + ((lane >> 4) << 3) + j;
    int g = n >> 6, c = n & 63;
    const float* W = (g < 3) ? (Wih + (size_t)l * 12288 + (size_t)(g * 64 + c) * 64)
                             : (Whh + (size_t)l * 12288 + (size_t)((g - 3) * 64 + c) * 64);
    float v = W[k];
    unsigned short h, lo;
    split_bf16(v, h, lo);
    WGhi[i2] = h; WGlo[i2] = lo;
  }
}

// ---------------------------------------------------------------------------
// ep for BOTH layers; self-loop mean division folded in. blockIdx.y = layer.
// ---------------------------------------------------------------------------
__global__ __launch_bounds__(256) void k_ep(
    const float* __restrict__ ea, const float* __restrict__ loopA,
    const float* __restrict__ We, const int* __restrict__ posOf,
    const float* __restrict__ cntF, float* __restrict__ EPc) {
  __shared__ float wlds[EFf * Hh];
  int tid = threadIdx.x;
  int l = blockIdx.y;
  const float* Wel = We + (size_t)l * EFf * Hh;
  if (tid < EFf * Hh) wlds[tid] = Wel[tid];
  if (tid + 256 < EFf * Hh) wlds[tid + 256] = Wel[tid + 256];
  __syncthreads();
  int idx = blockIdx.x * 256 + tid;
  int e = idx >> 6, j = idx & 63;
  const float* a = (e < Ee) ? (ea + (size_t)e * EFf) : (loopA + (size_t)(e - Ee) * EFf);
  float acc = 0.f;
#pragma unroll
  for (int k = 0; k < EFf; ++k) acc += a[k] * wlds[k * Hh + j];
  if (e >= Ee) acc /= fmaxf(cntF[e - Ee], 1.0f);
  EPc[(size_t)l * E2c * Hh + (((size_t)posOf[e]) << 6) + j] = acc;
}

// ---------------------------------------------------------------------------
// proj (R5 version): thread = 2 rows x 16 cols. grid (RTOT/512, 4)
// ---------------------------------------------------------------------------
__global__ __launch_bounds__(256) void k_proj(
    const float* __restrict__ X, const float* __restrict__ Wp,
    const float* __restrict__ bp, float* __restrict__ Out) {
  __shared__ float w[32 * 16];
  int tid = threadIdx.x;
  int j0 = blockIdx.y << 4;
  for (int idx = tid; idx < 32 * 16; idx += 256)
    w[idx] = Wp[((idx >> 4) << 6) + j0 + (idx & 15)];
  __syncthreads();
  int r0 = (blockIdx.x << 9) + tid;
  float acc[2][16];
#pragma unroll
  for (int jj = 0; jj < 16; ++jj) { float b = bp[j0 + jj]; acc[0][jj] = b; acc[1][jj] = b; }
  const float* x0 = X + ((size_t)r0 << 5);
  const float* x1 = x0 + (256 << 5);
  for (int kc = 0; kc < 8; ++kc) {
    float4 a0 = *(const float4*)(x0 + 4 * kc);
    float4 a1 = *(const float4*)(x1 + 4 * kc);
    float a0a[4] = {a0.x, a0.y, a0.z, a0.w};
    float a1a[4] = {a1.x, a1.y, a1.z, a1.w};
#pragma unroll
    for (int q = 0; q < 4; ++q) {
      const float4* wp4 = (const float4*)(w + ((4 * kc + q) << 4));
#pragma unroll
      for (int q4 = 0; q4 < 4; ++q4) {
        float4 wv = wp4[q4];
        acc[0][4*q4+0] = fmaf(a0a[q], wv.x, acc[0][4*q4+0]);
        acc[0][4*q4+1] = fmaf(a0a[q], wv.y, acc[0][4*q4+1]);
        acc[0][4*q4+2] = fmaf(a0a[q], wv.z, acc[0][4*q4+2]);
        acc[0][4*q4+3] = fmaf(a0a[q], wv.w, acc[0][4*q4+3]);
        acc[1][4*q4+0] = fmaf(a1a[q], wv.x, acc[1][4*q4+0]);
        acc[1][4*q4+1] = fmaf(a1a[q], wv.y, acc[1][4*q4+1]);
        acc[1][4*q4+2] = fmaf(a1a[q], wv.z, acc[1][4*q4+2]);
        acc[1][4*q4+3] = fmaf(a1a[q], wv.w, acc[1][4*q4+3]);
      }
    }
  }
#pragma unroll
  for (int rr = 0; rr < 2; ++rr) {
    float* op = Out + (((size_t)(r0 + 256 * rr)) << 6) + j0;
#pragma unroll
    for (int q4 = 0; q4 < 4; ++q4)
      *(float4*)(op + 4 * q4) = make_float4(acc[rr][4*q4], acc[rr][4*q4+1], acc[rr][4*q4+2], acc[rr][4*q4+3]);
  }
}

// ---------------------------------------------------------------------------
// XL/XR via bf16x3 MFMA (R14, measured good).
// ---------------------------------------------------------------------------
__global__ __launch_bounds__(256) void k_xlr_mm(
    const float* __restrict__ X,
    const unsigned short* __restrict__ WXhi, const unsigned short* __restrict__ WXlo,
    const float* __restrict__ bl_, const float* __restrict__ br_,
    float* __restrict__ XL, float* __restrict__ XR) {
  __shared__ unsigned short ahi[4096], alo[4096];
  __shared__ float cbuf[64 * CST];
  int tid = threadIdx.x, lane = tid & 63, wv = tid >> 6;
  size_t m0 = (size_t)blockIdx.x << 6;
#pragma unroll
  for (int it = 0; it < 2; ++it) {
    int task = (it << 8) + tid;
    int row = task >> 3, cOct = task & 7;
    const float* src = X + ((m0 + row) << 6) + (cOct << 3);
    float4 a = *(const float4*)src;
    float4 b = *(const float4*)(src + 4);
    float va[8] = {a.x, a.y, a.z, a.w, b.x, b.y, b.z, b.w};
    short8 hv, lv;
#pragma unroll
    for (int j = 0; j < 8; ++j) {
      unsigned short hs, ls;
      split_bf16(va[j], hs, ls);
      hv[j] = (short)hs; lv[j] = (short)ls;
    }
    int f = ((cOct >> 2) * 4 + (row >> 4)) * 64 + ((cOct & 3) << 4) + (row & 15);
    *(short8*)&ahi[f << 3] = hv;
    *(short8*)&alo[f << 3] = lv;
  }
  __syncthreads();
  short8 Ah0 = *(const short8*)&ahi[((0 + wv) << 6 | lane) << 3];
  short8 Al0 = *(const short8*)&alo[((0 + wv) << 6 | lane) << 3];
  short8 Ah1 = *(const short8*)&ahi[((4 + wv) << 6 | lane) << 3];
  short8 Al1 = *(const short8*)&alo[((4 + wv) << 6 | lane) << 3];
  int nl = lane & 15;
  f32x4 acc[8];
#pragma unroll
  for (int t = 0; t < 8; ++t) {
    int n = t * 16 + nl;
    float b = (n < 64) ? bl_[n] : br_[n - 64];
    acc[t] = (f32x4){b, b, b, b};
  }
#pragma unroll
  for (int t = 0; t < 8; ++t) {
    const short8* bh0p = (const short8*)(WXhi + ((t << 1) << 9)) + lane;
    const short8* bl0p = (const short8*)(WXlo + ((t << 1) << 9)) + lane;
    const short8* bh1p = (const short8*)(WXhi + (((t << 1) + 1) << 9)) + lane;
    const short8* bl1p = (const short8*)(WXlo + (((t << 1) + 1) << 9)) + lane;
    short8 bh0 = *bh0p, bl0 = *bl0p, bh1 = *bh1p, bl1 = *bl1p;
    acc[t] = MFMA16(Ah0, bh0, acc[t], 0, 0, 0);
    acc[t] = MFMA16(Ah0, bl0, acc[t], 0, 0, 0);
    acc[t] = MFMA16(Al0, bh0, acc[t], 0, 0, 0);
    acc[t] = MFMA16(Ah1, bh1, acc[t], 0, 0, 0);
    acc[t] = MFMA16(Ah1, bl1, acc[t], 0, 0, 0);
    acc[t] = MFMA16(Al1, bh1, acc[t], 0, 0, 0);
  }
  int rbase = (wv << 4) + ((lane >> 4) << 2);
#pragma unroll
  for (int half = 0; half < 2; ++half) {
    __syncthreads();
#pragma unroll
    for (int tt = 0; tt < 4; ++tt) {
      int t = (half << 2) + tt;
#pragma unroll
      for (int reg = 0; reg < 4; ++reg)
        cbuf[(rbase + reg) * CST + (tt << 4) + nl] = acc[t][reg];
    }
    __syncthreads();
    float* dst = half ? XR : XL;
#pragma unroll
    for (int i = 0; i < 4; ++i) {
      int idx = (i << 10) + (tid << 2);
      int row = idx >> 6, col = idx & 63;
      *(float4*)(dst + ((m0 + row) << 6) + col) = *(float4*)&cbuf[row * CST + col];
    }
  }
}

// ---------------------------------------------------------------------------
// GATv2 v6 (R15/R16): block = (dst d, graph octet q).
// ---------------------------------------------------------------------------
__global__ __launch_bounds__(256) void k_gat(
    const float* __restrict__ XL, float* __restrict__ XR_HG,
    const float* __restrict__ EPc, const int* __restrict__ offs,
    const int* __restrict__ srcA,
    const float* __restrict__ att, const float* __restrict__ gbl) {
  int d = blockIdx.x;
  int q = blockIdx.y;
  int tid = threadIdx.x;
  int wv = tid >> 6, lane = tid & 63;
  int eSub = lane >> 3, hOct = lane & 7;
  int hb = hOct << 3;
  float at[8], gv[8];
  {
    float4 a0 = *(const float4*)(att + hb);
    float4 a1 = *(const float4*)(att + hb + 4);
    float4 g0v = *(const float4*)(gbl + hb);
    float4 g1v = *(const float4*)(gbl + hb + 4);
    at[0]=a0.x; at[1]=a0.y; at[2]=a0.z; at[3]=a0.w;
    at[4]=a1.x; at[5]=a1.y; at[6]=a1.z; at[7]=a1.w;
    gv[0]=g0v.x; gv[1]=g0v.y; gv[2]=g0v.z; gv[3]=g0v.w;
    gv[4]=g1v.x; gv[5]=g1v.y; gv[6]=g1v.z; gv[7]=g1v.w;
  }
  int p0 = offs[d], p1 = offs[d + 1];
  int nE = p1 - p0;
  int nCh = (nE + 7) >> 3;
  int g0 = (q << 3) + wv;
  int g1 = g0 + 4;
  size_t rowA = ((size_t)(g0 * Nn + d)) << 6;
  size_t rowB = ((size_t)(g1 * Nn + d)) << 6;
  float xrA[8], xrB[8];
  {
    float4 a = *(const float4*)(XR_HG + rowA + hb);
    float4 b = *(const float4*)(XR_HG + rowA + hb + 4);
    float4 c = *(const float4*)(XR_HG + rowB + hb);
    float4 e = *(const float4*)(XR_HG + rowB + hb + 4);
    xrA[0]=a.x; xrA[1]=a.y; xrA[2]=a.z; xrA[3]=a.w; xrA[4]=b.x; xrA[5]=b.y; xrA[6]=b.z; xrA[7]=b.w;
    xrB[0]=c.x; xrB[1]=c.y; xrB[2]=c.z; xrB[3]=c.w; xrB[4]=e.x; xrB[5]=e.y; xrB[6]=e.z; xrB[7]=e.w;
  }
  const float* XA = XL + (((size_t)g0 * Nn) << 6);
  const float* XB = XL + (((size_t)g1 * Nn) << 6);
  float SsA = 0.f, SsB = 0.f;
  float accA[8], accB[8];
#pragma unroll
  for (int j = 0; j < 8; ++j) { accA[j] = 0.f; accB[j] = 0.f; }
  for (int c = 0; c < nCh; ++c) {
    int p = (c << 3) + eSub;
    int pc = p < nE ? p : nE - 1;
    int s = srcA[p0 + pc];
    const float* epp = EPc + (((size_t)(p0 + pc)) << 6) + hb;
    float4 e0 = *(const float4*)epp;
    float4 e1 = *(const float4*)(epp + 4);
    float ep[8] = {e0.x, e0.y, e0.z, e0.w, e1.x, e1.y, e1.z, e1.w};
    const float* xap = XA + ((size_t)s << 6) + hb;
    const float* xbp = XB + ((size_t)s << 6) + hb;
    float4 xa0 = *(const float4*)xap, xa1 = *(const float4*)(xap + 4);
    float4 xb0 = *(const float4*)xbp, xb1 = *(const float4*)(xbp + 4);
    float xA[8] = {xa0.x, xa0.y, xa0.z, xa0.w, xa1.x, xa1.y, xa1.z, xa1.w};
    float xB[8] = {xb0.x, xb0.y, xb0.z, xb0.w, xb1.x, xb1.y, xb1.z, xb1.w};
    float vA = 0.f, vB = 0.f;
#pragma unroll
    for (int j = 0; j < 8; ++j) {
      float mA = xA[j] + xrA[j] + ep[j];
      mA = fmaxf(mA, 0.2f * mA);
      vA = fmaf(mA, at[j], vA);
      float mB = xB[j] + xrB[j] + ep[j];
      mB = fmaxf(mB, 0.2f * mB);
      vB = fmaf(mB, at[j], vB);
    }
    vA = redlogit(vA);
    vB = redlogit(vB);
    float wA = (p < nE) ? __expf(vA) : 0.f;
    float wB = (p < nE) ? __expf(vB) : 0.f;
    SsA += wA; SsB += wB;
#pragma unroll
    for (int j = 0; j < 8; ++j) {
      accA[j] = fmaf(wA, xA[j], accA[j]);
      accB[j] = fmaf(wB, xB[j], accB[j]);
    }
  }
  SsA = red8(SsA); SsB = red8(SsB);
#pragma unroll
  for (int j = 0; j < 8; ++j) { accA[j] = red8(accA[j]); accB[j] = red8(accB[j]); }
  if (eSub == 0) {
    float invA = 1.f / SsA, invB = 1.f / SsB;
    float* opA = XR_HG + rowA + hb;
    float* opB = XR_HG + rowB + hb;
    *(float4*)(opA)     = make_float4(fmaf(accA[0], invA, gv[0]), fmaf(accA[1], invA, gv[1]),
                                      fmaf(accA[2], invA, gv[2]), fmaf(accA[3], invA, gv[3]));
    *(float4*)(opA + 4) = make_float4(fmaf(accA[4], invA, gv[4]), fmaf(accA[5], invA, gv[5]),
                                      fmaf(accA[6], invA, gv[6]), fmaf(accA[7], invA, gv[7]));
    *(float4*)(opB)     = make_float4(fmaf(accB[0], invB, gv[0]), fmaf(accB[1], invB, gv[1]),
                                      fmaf(accB[2], invB, gv[2]), fmaf(accB[3], invB, gv[3]));
    *(float4*)(opB + 4) = make_float4(fmaf(accB[4], invB, gv[4]), fmaf(accB[5], invB, gv[5]),
                                      fmaf(accB[6], invB, gv[6]), fmaf(accB[7], invB, gv[7]));
  }
}

// ---------------------------------------------------------------------------
// Per-t fused GRU via bf16x3 MFMA (R14, measured good).
// ---------------------------------------------------------------------------
template <int HASP>
__global__ __launch_bounds__(256) void k_gru_mm(
    const float* __restrict__ hg, const float* __restrict__ hp,
    const unsigned short* __restrict__ WGhi, const unsigned short* __restrict__ WGlo,
    const float* __restrict__ bih, const float* __restrict__ bhh,
    float* __restrict__ hout) {
  __shared__ unsigned short ghi[4096], glo[4096], phi[4096], plo[4096];
  __shared__ float cbuf[64 * CST];
  int tid = threadIdx.x, lane = tid & 63, wv = tid >> 6;
  size_t m0 = (size_t)blockIdx.x << 6;
#pragma unroll
  for (int it = 0; it < 2; ++it) {
    int task = (it << 8) + tid;
    int row = task >> 3, cOct = task & 7;
    const float* srcg = hg + ((m0 + row) << 6) + (cOct << 3);
    float4 a = *(const float4*)srcg;
    float4 b = *(const float4*)(srcg + 4);
    float va[8] = {a.x, a.y, a.z, a.w, b.x, b.y, b.z, b.w};
    short8 hv, lv;
#pragma unroll
    for (int j = 0; j < 8; ++j) {
      unsigned short hs, ls;
      split_bf16(va[j], hs, ls);
      hv[j] = (short)hs; lv[j] = (short)ls;
    }
    int f = ((cOct >> 2) * 4 + (row >> 4)) * 64 + ((cOct & 3) << 4) + (row & 15);
    *(short8*)&ghi[f << 3] = hv;
    *(short8*)&glo[f << 3] = lv;
    if (HASP) {
      const float* srcp = hp + ((m0 + row) << 6) + (cOct << 3);
      float4 c = *(const float4*)srcp;
      float4 e = *(const float4*)(srcp + 4);
      float vp[8] = {c.x, c.y, c.z, c.w, e.x, e.y, e.z, e.w};
#pragma unroll
      for (int j = 0; j < 8; ++j) {
        unsigned short hs, ls;
        split_bf16(vp[j], hs, ls);
        hv[j] = (short)hs; lv[j] = (short)ls;
      }
      *(short8*)&phi[f << 3] = hv;
      *(short8*)&plo[f << 3] = lv;
    }
  }
  __syncthreads();
  short8 Gh0 = *(const short8*)&ghi[((0 + wv) << 6 | lane) << 3];
  short8 Gl0 = *(const short8*)&glo[((0 + wv) << 6 | lane) << 3];
  short8 Gh1 = *(const short8*)&ghi[((4 + wv) << 6 | lane) << 3];
  short8 Gl1 = *(const short8*)&glo[((4 + wv) << 6 | lane) << 3];
  short8 Ph0, Pl0, Ph1, Pl1;
  if (HASP) {
    Ph0 = *(const short8*)&phi[((0 + wv) << 6 | lane) << 3];
    Pl0 = *(const short8*)&plo[((0 + wv) << 6 | lane) << 3];
    Ph1 = *(const short8*)&phi[((4 + wv) << 6 | lane) << 3];
    Pl1 = *(const short8*)&plo[((4 + wv) << 6 | lane) << 3];
  }
  int nl = lane & 15;
  f32x4 acc[24];
#pragma unroll
  for (int t = 0; t < 24; ++t) {
    int g = t >> 2;
    int c = ((t & 3) << 4) + nl;
    float b = (g < 3) ? bih[(g << 6) + c] : bhh[((g - 3) << 6) + c];
    acc[t] = (f32x4){b, b, b, b};
  }
#pragma unroll
  for (int t = 0; t < 12; ++t) {
    const short8* bh0p = (const short8*)(WGhi + ((t << 1) << 9)) + lane;
    const short8* bl0p = (const short8*)(WGlo + ((t << 1) << 9)) + lane;
    const short8* bh1p = (const short8*)(WGhi + (((t << 1) + 1) << 9)) + lane;
    const short8* bl1p = (const short8*)(WGlo + (((t << 1) + 1) << 9)) + lane;
    short8 bh0 = *bh0p, bl0 = *bl0p, bh1 = *bh1p, bl1 = *bl1p;
    acc[t] = MFMA16(Gh0, bh0, acc[t], 0, 0, 0);
    acc[t] = MFMA16(Gh0, bl0, acc[t], 0, 0, 0);
    acc[t] = MFMA16(Gl0, bh0, acc[t], 0, 0, 0);
    acc[t] = MFMA16(Gh1, bh1, acc[t], 0, 0, 0);
    acc[t] = MFMA16(Gh1, bl1, acc[t], 0, 0, 0);
    acc[t] = MFMA16(Gl1, bh1, acc[t], 0, 0, 0);
  }
  if (HASP) {
#pragma unroll
    for (int t = 12; t < 24; ++t) {
      const short8* bh0p = (const short8*)(WGhi + ((t << 1) << 9)) + lane;
      const short8* bl0p = (const short8*)(WGlo + ((t << 1) << 9)) + lane;
      const short8* bh1p = (const short8*)(WGhi + (((t << 1) + 1) << 9)) + lane;
      const short8* bl1p = (const short8*)(WGlo + (((t << 1) + 1) << 9)) + lane;
      short8 bh0 = *bh0p, bl0 = *bl0p, bh1 = *bh1p, bl1 = *bl1p;
      acc[t] = MFMA16(Ph0, bh0, acc[t], 0, 0, 0);
      acc[t] = MFMA16(Ph0, bl0, acc[t], 0, 0, 0);
      acc[t] = MFMA16(Pl0, bh0, acc[t], 0, 0, 0);
      acc[t] = MFMA16(Ph1, bh1, acc[t], 0, 0, 0);
      acc[t] = MFMA16(Ph1, bl1, acc[t], 0, 0, 0);
      acc[t] = MFMA16(Pl1, bh1, acc[t], 0, 0, 0);
    }
  }
  int rbase = (wv << 4) + ((lane >> 4) << 2);
#pragma unroll
  for (int ct = 0; ct < 4; ++ct) {
    int c = (ct << 4) + nl;
#pragma unroll
    for (int reg = 0; reg < 4; ++reg) {
      size_t rowg = m0 + rbase + reg;
      float rg = sigf(acc[ct][reg]      + acc[12 + ct][reg]);
      float zg = sigf(acc[4 + ct][reg]  + acc[16 + ct][reg]);
      float ng = tanhfast(acc[8 + ct][reg] + rg * acc[20 + ct][reg]);
      float hv = HASP ? hp[(rowg << 6) + c] : 0.f;
      cbuf[(rbase + reg) * CST + c] = (1.f - zg) * ng + zg * hv;
    }
  }
  __syncthreads();
#pragma unroll
  for (int i = 0; i < 4; ++i) {
    int idx = (i << 10) + (tid << 2);
    int row = idx >> 6, col = idx & 63;
    *(float4*)(hout + ((m0 + row) << 6) + col) = *(float4*)&cbuf[row * CST + col];
  }
}

// ---------------------------------------------------------------------------
// Heads v2: 128 blocks x 64 rows. X staged coalesced (rows contiguous per b);
// thread = (row, 8-wide j-group); W reads wave-uniform (jg = tid>>6 constant
// per wave). Partials reduced through LDS.
// ---------------------------------------------------------------------------
__global__ __launch_bounds__(256) void k_heads(
    const float* __restrict__ Xb,
    const float* __restrict__ oW1, const float* __restrict__ ob1,
    const float* __restrict__ oW2, const float* __restrict__ ob2,
    const float* __restrict__ dW1, const float* __restrict__ db1,
    const float* __restrict__ dW2, const float* __restrict__ db2,
    float* __restrict__ out) {
  __shared__ float xa[64 * 65];
  __shared__ float w1o[64 * 32], w1d[64 * 32];
  __shared__ float po[4][64], pd[4][64];
  int tid = threadIdx.x;
  int rblk = blockIdx.x << 6;              // 64 rows
  int b = rblk >> 11;
  int n0 = rblk & (Nn - 1);
  const float* src = Xb + (((size_t)b * Ss + (Ss - 1)) * Nn + n0) * Hh;
  // stage X: 64x64 contiguous floats, scalar stores into stride-65 LDS
#pragma unroll
  for (int i = 0; i < 4; ++i) {
    int idx = (i << 10) + (tid << 2);
    int row = idx >> 6, col = idx & 63;
    float4 v = *(const float4*)(src + idx);
    float* dp = &xa[row * 65 + col];
    dp[0] = v.x; dp[1] = v.y; dp[2] = v.z; dp[3] = v.w;
  }
  for (int idx = tid; idx < 2048; idx += 256) {
    w1o[idx] = oW1[idx];
    w1d[idx] = dW1[idx];
  }
  __syncthreads();
  int row = tid & 63;
  int jg = tid >> 6;                       // wave-uniform
  int j0 = jg << 3;
  float hO[8], hD[8];
#pragma unroll
  for (int j = 0; j < 8; ++j) { hO[j] = ob1[j0 + j]; hD[j] = db1[j0 + j]; }
  const float* xr = &xa[row * 65];
  for (int k = 0; k < 64; ++k) {
    float xv = xr[k];
    const float4* wo = (const float4*)&w1o[(k << 5) + j0];
    const float4* wd = (const float4*)&w1d[(k << 5) + j0];
    float4 o0 = wo[0], o1 = wo[1], d0 = wd[0], d1 = wd[1];
    hO[0] = fmaf(xv, o0.x, hO[0]); hO[1] = fmaf(xv, o0.y, hO[1]);
    hO[2] = fmaf(xv, o0.z, hO[2]); hO[3] = fmaf(xv, o0.w, hO[3]);
    hO[4] = fmaf(xv, o1.x, hO[4]); hO[5] = fmaf(xv, o1.y, hO[5]);
    hO[6] = fmaf(xv, o1.z, hO[6]); hO[7] = fmaf(xv, o1.w, hO[7]);
    hD[0] = fmaf(xv, d0.x, hD[0]); hD[1] = fmaf(xv, d0.y, hD[1]);
    hD[2] = fmaf(xv, d0.z, hD[2]); hD[3] = fmaf(xv, d0.w, hD[3]);
    hD[4] = fmaf(xv, d1.x, hD[4]); hD[5] = fmaf(xv, d1.y, hD[5]);
    hD[6] = fmaf(xv, d1.z, hD[6]); hD[7] = fmaf(xv, d1.w, hD[7]);
  }
  float accoP = 0.f, accdP = 0.f;
#pragma unroll
  for (int j = 0; j < 8; ++j) {
    accoP = fmaf(fmaxf(hO[j], 0.f), oW2[j0 + j], accoP);
    accdP = fmaf(fmaxf(hD[j], 0.f), dW2[j0 + j], accdP);
  }
  po[jg][row] = accoP;
  pd[jg][row] = accdP;
  __syncthreads();
  if (tid < 64) {
    int r = rblk + tid;
    out[r]           = ob2[0] + ((po[0][tid] + po[1][tid]) + (po[2][tid] + po[3][tid]));
    out[Bb * Nn + r] = db2[0] + ((pd[0][tid] + pd[1][tid]) + (pd[2][tid] + pd[3][tid]));
  }
}

// ---------------------------------------------------------------------------
extern "C" void kernel_launch(void* const* d_in, const int* in_sizes, int n_in,
                              void* d_out, int out_size, void* d_ws, size_t ws_size,
                              hipStream_t stream) {
  const float* x   = (const float*)d_in[0];
  const int*   ei  = (const int*)d_in[1];
  const float* ea  = (const float*)d_in[2];
  const float* Wp  = (const float*)d_in[3];
  const float* bp  = (const float*)d_in[4];
  const float* Wl  = (const float*)d_in[5];
  const float* bl  = (const float*)d_in[6];
  const float* Wr  = (const float*)d_in[7];
  const float* br  = (const float*)d_in[8];
  const float* We  = (const float*)d_in[9];
  const float* att = (const float*)d_in[10];
  const float* gb  = (const float*)d_in[11];
  const float* Wih = (const float*)d_in[12];
  const float* Whh = (const float*)d_in[13];
  const float* bih = (const float*)d_in[14];
  const float* bhh = (const float*)d_in[15];
  const float* oW1 = (const float*)d_in[16];
  const float* ob1 = (const float*)d_in[17];
  const float* oW2 = (const float*)d_in[18];
  const float* ob2 = (const float*)d_in[19];
  const float* dW1 = (const float*)d_in[20];
  const float* db1 = (const float*)d_in[21];
  const float* dW2 = (const float*)d_in[22];
  const float* db2 = (const float*)d_in[23];
  float* out = (float*)d_out;

  // workspace layout
  float* f    = (float*)d_ws;
  float* Xb   = f;                          // RTOT*64
  float* XLb  = Xb  + (size_t)RTOT * Hh;
  float* XRb  = XLb + (size_t)RTOT * Hh;    // hg after k_gat
  float* EPc  = XRb + (size_t)RTOT * Hh;    // 2 * E2c * 64 (CSR order, both layers)
  unsigned short* WXhi = (unsigned short*)(EPc + (size_t)2 * E2c * Hh); // 16384
  unsigned short* WXlo = WXhi + 16384;
  unsigned short* WGhi = WXlo + 16384;      // 49152
  unsigned short* WGlo = WGhi + 49152;
  float* cntF = (float*)(WGlo + 49152);     // 2048
  float* loopA = cntF + Nn;                 // 2048*8
  int*   fillI = (int*)(loopA + Nn * EFf);  // 2048
  int*   offs  = fillI + Nn;                // 2049 (+pad)
  int*   posOf = offs + 2052;               // 18432
  int*   srcA  = posOf + E2c;               // 18432

  hipMemsetAsync(cntF, 0, (size_t)(Nn + Nn * EFf + Nn) * 4, stream);

  k_loop_accum<<<dim3(Ee * EFf / 256), 256, 0, stream>>>(ei, ea, cntF, loopA);
  k_scan<<<1, 256, 0, stream>>>(cntF, offs);
  k_scatter<<<dim3((E2c + 255) / 256), 256, 0, stream>>>(ei, offs, fillI, posOf, srcA);
  k_wprep<<<dim3(256), 256, 0, stream>>>(Wl, Wr, Wih, Whh, WXhi, WXlo, WGhi, WGlo);

  // X = x @ Wp + bp
  k_proj<<<dim3(RTOT / 512, 4), 256, 0, stream>>>(x, Wp, bp, Xb);

  // ep for both layers (division by cnt folded in)
  k_ep<<<dim3(E2c * Hh / 256, 2), 256, 0, stream>>>(ea, loopA, We, posOf, cntF, EPc);

  for (int l = 0; l < 2; ++l) {
    k_xlr_mm<<<dim3(RTOT / 64), 256, 0, stream>>>(
        Xb, WXhi + (size_t)l * 8192, WXlo + (size_t)l * 8192,
        bl + (size_t)l * Hh, br + (size_t)l * Hh, XLb, XRb);
    k_gat<<<dim3(Nn, 8), 256, 0, stream>>>(
        XLb, XRb, EPc + (size_t)l * E2c * Hh, offs, srcA,
        att + (size_t)l * Hh, gb + (size_t)l * Hh);
    const unsigned short* WGh_l = WGhi + (size_t)l * 24576;
    const unsigned short* WGl_l = WGlo + (size_t)l * 24576;
    const float* bih_l = bih + (size_t)l * 192;
    const float* bhh_l = bhh + (size_t)l * 192;
    for (int t = 0; t < Bb; ++t) {
      const float* hg_t = XRb + (size_t)t * Mm * Hh;
      float* h_out = Xb + (size_t)t * Mm * Hh;
      if (t == 0) {
        k_gru_mm<0><<<dim3(Mm / 64), 256, 0, stream>>>(
            hg_t, nullptr, WGh_l, WGl_l, bih_l, bhh_l, h_out);
      } else {
        const float* h_prev = Xb + (size_t)(t - 1) * Mm * Hh;
        k_gru_mm<1><<<dim3(Mm / 64), 256, 0, stream>>>(
            hg_t, h_prev, WGh_l, WGl_l, bih_l, bhh_l, h_out);
      }
    }
  }

  k_heads<<<dim3(Bb * Nn / 64), 256, 0, stream>>>(
      Xb, oW1, ob1, oW2, ob2, dW1, db1, dW2, db2, out);
}

// Round 18
// 421.991 us; speedup vs baseline: 1.3667x; 1.0072x over previous
//
#include <hip/hip_runtime.h>
#include <math.h>

#define Bb   4
#define Ss   16
#define Nn   2048
#define Ff   32
#define Ee   16384
#define EFf  8
#define Hh   64
#define HB2  32
#define E2c  (Ee + Nn)          // 18432
#define RTOT (Bb*Ss*Nn)         // 131072 (64 graphs x 2048)
#define Mm   (Ss*Nn)            // 32768
#define CST  68                 // xlr cbuf row stride
#define GST  36                 // gru cbuf row stride (32 cols + pad)

typedef __attribute__((ext_vector_type(8))) short short8;
typedef __attribute__((ext_vector_type(4))) float f32x4;
#define MFMA16 __builtin_amdgcn_mfma_f32_16x16x32_bf16

__device__ __forceinline__ float sigf(float x) { return 1.f / (1.f + __expf(-x)); }
__device__ __forceinline__ float tanhfast(float x) { return 2.f / (1.f + __expf(-2.f * x)) - 1.f; }

__device__ __forceinline__ void split_bf16(float x, unsigned short& h, unsigned short& l) {
  unsigned u = __float_as_uint(x);
  unsigned r = (u + 0x7FFFu + ((u >> 16) & 1u)) >> 16;
  h = (unsigned short)r;
  float rest = x - __uint_as_float(r << 16);
  unsigned u2 = __float_as_uint(rest);
  l = (unsigned short)((u2 + 0x7FFFu + ((u2 >> 16) & 1u)) >> 16);
}

template <int PAT>
__device__ __forceinline__ float xorf(float v) {
  return __int_as_float(__builtin_amdgcn_ds_swizzle(__float_as_int(v), PAT));
}
__device__ __forceinline__ float red8(float v) {
  int x = __builtin_amdgcn_update_dpp(0, __float_as_int(v), 0x128, 0xF, 0xF, true);
  v += __int_as_float(x);
  v += xorf<0x401F>(v);
  v += __shfl_xor(v, 32, 64);
  return v;
}
__device__ __forceinline__ float redlogit(float v) {
  int x;
  x = __builtin_amdgcn_update_dpp(0, __float_as_int(v), 0xB1, 0xF, 0xF, true);
  v += __int_as_float(x);
  x = __builtin_amdgcn_update_dpp(0, __float_as_int(v), 0x4E, 0xF, 0xF, true);
  v += __int_as_float(x);
  v += xorf<0x101F>(v);
  return v;
}

// ---------------------------------------------------------------------------
__global__ __launch_bounds__(256) void k_loop_accum(
    const int* __restrict__ ei, const float* __restrict__ ea,
    float* __restrict__ cntF, float* __restrict__ loopA) {
  int idx = blockIdx.x * 256 + threadIdx.x;
  int e = idx >> 3, j = idx & 7;
  int d = ei[Ee + e];
  atomicAdd(&loopA[d * EFf + j], ea[idx]);
  if (j == 0) atomicAdd(&cntF[d], 1.0f);
}

// ---------------------------------------------------------------------------
__global__ __launch_bounds__(256) void k_scan(
    const float* __restrict__ cntF, int* __restrict__ offs) {
  __shared__ int partial[256];
  int tid = threadIdx.x;
  int base = tid * 8;
  int vals[8];
  int s = 0;
  for (int i = 0; i < 8; ++i) {
    int c = (int)cntF[base + i] + 1;
    vals[i] = c;
    s += c;
  }
  partial[tid] = s;
  __syncthreads();
  for (int off = 1; off < 256; off <<= 1) {
    int v = partial[tid];
    int add = (tid >= off) ? partial[tid - off] : 0;
    __syncthreads();
    partial[tid] = v + add;
    __syncthreads();
  }
  int run = (tid == 0) ? 0 : partial[tid - 1];
  for (int i = 0; i < 8; ++i) {
    offs[base + i] = run;
    run += vals[i];
  }
  if (tid == 255) offs[Nn] = run;
}

__global__ __launch_bounds__(256) void k_scatter(
    const int* __restrict__ ei, const int* __restrict__ offs,
    int* __restrict__ fillI, int* __restrict__ posOf, int* __restrict__ srcA) {
  int e = blockIdx.x * 256 + threadIdx.x;
  if (e >= E2c) return;
  int d = (e < Ee) ? ei[Ee + e] : (e - Ee);
  int s = (e < Ee) ? ei[e]      : (e - Ee);
  int pos = offs[d] + atomicAdd(&fillI[d], 1);
  posOf[e] = pos;
  srcA[pos] = s;
}

// ---------------------------------------------------------------------------
// Pre-split + pre-swizzle weights into MFMA B-fragment order (R9 layout).
// ---------------------------------------------------------------------------
__global__ __launch_bounds__(256) void k_wprep(
    const float* __restrict__ Wl, const float* __restrict__ Wr,
    const float* __restrict__ Wih, const float* __restrict__ Whh,
    unsigned short* __restrict__ WXhi, unsigned short* __restrict__ WXlo,
    unsigned short* __restrict__ WGhi, unsigned short* __restrict__ WGlo) {
  int idx = blockIdx.x * 256 + threadIdx.x;   // 65536 total
  if (idx < 16384) {
    int j = idx & 7, lane = (idx >> 3) & 63, kh = (idx >> 9) & 1;
    int t = (idx >> 10) & 7, l = idx >> 13;
    int n = t * 16 + (lane & 15);
    int k = kh * 32 + ((lane >> 4) << 3) + j;
    const float* W = (n < 64) ? (Wl + (size_t)l * 4096) : (Wr + (size_t)l * 4096);
    float v = W[k * 64 + (n & 63)];
    unsigned short h, lo;
    split_bf16(v, h, lo);
    WXhi[idx] = h; WXlo[idx] = lo;
  } else {
    int i2 = idx - 16384;                     // < 49152
    int j = i2 & 7, lane = (i2 >> 3) & 63, kh = (i2 >> 9) & 1;
    int t = (i2 >> 10) % 24, l = i2 / 24576;
    int n = t * 16 + (lane & 15);
    int k = kh * 32 + ((lane >> 4) << 3) + j;
    int g = n >> 6, c = n & 63;
    const float* W = (g < 3) ? (Wih + (size_t)l * 12288 + (size_t)(g * 64 + c) * 64)
                             : (Whh + (size_t)l * 12288 + (size_t)((g - 3) * 64 + c) * 64);
    float v = W[k];
    unsigned short h, lo;
    split_bf16(v, h, lo);
    WGhi[i2] = h; WGlo[i2] = lo;
  }
}

// ---------------------------------------------------------------------------
// ep for BOTH layers; self-loop mean division folded in. blockIdx.y = layer.
// ---------------------------------------------------------------------------
__global__ __launch_bounds__(256) void k_ep(
    const float* __restrict__ ea, const float* __restrict__ loopA,
    const float* __restrict__ We, const int* __restrict__ posOf,
    const float* __restrict__ cntF, float* __restrict__ EPc) {
  __shared__ float wlds[EFf * Hh];
  int tid = threadIdx.x;
  int l = blockIdx.y;
  const float* Wel = We + (size_t)l * EFf * Hh;
  if (tid < EFf * Hh) wlds[tid] = Wel[tid];
  if (tid + 256 < EFf * Hh) wlds[tid + 256] = Wel[tid + 256];
  __syncthreads();
  int idx = blockIdx.x * 256 + tid;
  int e = idx >> 6, j = idx & 63;
  const float* a = (e < Ee) ? (ea + (size_t)e * EFf) : (loopA + (size_t)(e - Ee) * EFf);
  float acc = 0.f;
#pragma unroll
  for (int k = 0; k < EFf; ++k) acc += a[k] * wlds[k * Hh + j];
  if (e >= Ee) acc /= fmaxf(cntF[e - Ee], 1.0f);
  EPc[(size_t)l * E2c * Hh + (((size_t)posOf[e]) << 6) + j] = acc;
}

// ---------------------------------------------------------------------------
// proj (R5 version): thread = 2 rows x 16 cols. grid (RTOT/512, 4)
// ---------------------------------------------------------------------------
__global__ __launch_bounds__(256) void k_proj(
    const float* __restrict__ X, const float* __restrict__ Wp,
    const float* __restrict__ bp, float* __restrict__ Out) {
  __shared__ float w[32 * 16];
  int tid = threadIdx.x;
  int j0 = blockIdx.y << 4;
  for (int idx = tid; idx < 32 * 16; idx += 256)
    w[idx] = Wp[((idx >> 4) << 6) + j0 + (idx & 15)];
  __syncthreads();
  int r0 = (blockIdx.x << 9) + tid;
  float acc[2][16];
#pragma unroll
  for (int jj = 0; jj < 16; ++jj) { float b = bp[j0 + jj]; acc[0][jj] = b; acc[1][jj] = b; }
  const float* x0 = X + ((size_t)r0 << 5);
  const float* x1 = x0 + (256 << 5);
  for (int kc = 0; kc < 8; ++kc) {
    float4 a0 = *(const float4*)(x0 + 4 * kc);
    float4 a1 = *(const float4*)(x1 + 4 * kc);
    float a0a[4] = {a0.x, a0.y, a0.z, a0.w};
    float a1a[4] = {a1.x, a1.y, a1.z, a1.w};
#pragma unroll
    for (int q = 0; q < 4; ++q) {
      const float4* wp4 = (const float4*)(w + ((4 * kc + q) << 4));
#pragma unroll
      for (int q4 = 0; q4 < 4; ++q4) {
        float4 wv = wp4[q4];
        acc[0][4*q4+0] = fmaf(a0a[q], wv.x, acc[0][4*q4+0]);
        acc[0][4*q4+1] = fmaf(a0a[q], wv.y, acc[0][4*q4+1]);
        acc[0][4*q4+2] = fmaf(a0a[q], wv.z, acc[0][4*q4+2]);
        acc[0][4*q4+3] = fmaf(a0a[q], wv.w, acc[0][4*q4+3]);
        acc[1][4*q4+0] = fmaf(a1a[q], wv.x, acc[1][4*q4+0]);
        acc[1][4*q4+1] = fmaf(a1a[q], wv.y, acc[1][4*q4+1]);
        acc[1][4*q4+2] = fmaf(a1a[q], wv.z, acc[1][4*q4+2]);
        acc[1][4*q4+3] = fmaf(a1a[q], wv.w, acc[1][4*q4+3]);
      }
    }
  }
#pragma unroll
  for (int rr = 0; rr < 2; ++rr) {
    float* op = Out + (((size_t)(r0 + 256 * rr)) << 6) + j0;
#pragma unroll
    for (int q4 = 0; q4 < 4; ++q4)
      *(float4*)(op + 4 * q4) = make_float4(acc[rr][4*q4], acc[rr][4*q4+1], acc[rr][4*q4+2], acc[rr][4*q4+3]);
  }
}

// ---------------------------------------------------------------------------
// XL/XR via bf16x3 MFMA (R14, measured good).
// ---------------------------------------------------------------------------
__global__ __launch_bounds__(256) void k_xlr_mm(
    const float* __restrict__ X,
    const unsigned short* __restrict__ WXhi, const unsigned short* __restrict__ WXlo,
    const float* __restrict__ bl_, const float* __restrict__ br_,
    float* __restrict__ XL, float* __restrict__ XR) {
  __shared__ unsigned short ahi[4096], alo[4096];
  __shared__ float cbuf[64 * CST];
  int tid = threadIdx.x, lane = tid & 63, wv = tid >> 6;
  size_t m0 = (size_t)blockIdx.x << 6;
#pragma unroll
  for (int it = 0; it < 2; ++it) {
    int task = (it << 8) + tid;
    int row = task >> 3, cOct = task & 7;
    const float* src = X + ((m0 + row) << 6) + (cOct << 3);
    float4 a = *(const float4*)src;
    float4 b = *(const float4*)(src + 4);
    float va[8] = {a.x, a.y, a.z, a.w, b.x, b.y, b.z, b.w};
    short8 hv, lv;
#pragma unroll
    for (int j = 0; j < 8; ++j) {
      unsigned short hs, ls;
      split_bf16(va[j], hs, ls);
      hv[j] = (short)hs; lv[j] = (short)ls;
    }
    int f = ((cOct >> 2) * 4 + (row >> 4)) * 64 + ((cOct & 3) << 4) + (row & 15);
    *(short8*)&ahi[f << 3] = hv;
    *(short8*)&alo[f << 3] = lv;
  }
  __syncthreads();
  short8 Ah0 = *(const short8*)&ahi[((0 + wv) << 6 | lane) << 3];
  short8 Al0 = *(const short8*)&alo[((0 + wv) << 6 | lane) << 3];
  short8 Ah1 = *(const short8*)&ahi[((4 + wv) << 6 | lane) << 3];
  short8 Al1 = *(const short8*)&alo[((4 + wv) << 6 | lane) << 3];
  int nl = lane & 15;
  f32x4 acc[8];
#pragma unroll
  for (int t = 0; t < 8; ++t) {
    int n = t * 16 + nl;
    float b = (n < 64) ? bl_[n] : br_[n - 64];
    acc[t] = (f32x4){b, b, b, b};
  }
#pragma unroll
  for (int t = 0; t < 8; ++t) {
    const short8* bh0p = (const short8*)(WXhi + ((t << 1) << 9)) + lane;
    const short8* bl0p = (const short8*)(WXlo + ((t << 1) << 9)) + lane;
    const short8* bh1p = (const short8*)(WXhi + (((t << 1) + 1) << 9)) + lane;
    const short8* bl1p = (const short8*)(WXlo + (((t << 1) + 1) << 9)) + lane;
    short8 bh0 = *bh0p, bl0 = *bl0p, bh1 = *bh1p, bl1 = *bl1p;
    acc[t] = MFMA16(Ah0, bh0, acc[t], 0, 0, 0);
    acc[t] = MFMA16(Ah0, bl0, acc[t], 0, 0, 0);
    acc[t] = MFMA16(Al0, bh0, acc[t], 0, 0, 0);
    acc[t] = MFMA16(Ah1, bh1, acc[t], 0, 0, 0);
    acc[t] = MFMA16(Ah1, bl1, acc[t], 0, 0, 0);
    acc[t] = MFMA16(Al1, bh1, acc[t], 0, 0, 0);
  }
  int rbase = (wv << 4) + ((lane >> 4) << 2);
#pragma unroll
  for (int half = 0; half < 2; ++half) {
    __syncthreads();
#pragma unroll
    for (int tt = 0; tt < 4; ++tt) {
      int t = (half << 2) + tt;
#pragma unroll
      for (int reg = 0; reg < 4; ++reg)
        cbuf[(rbase + reg) * CST + (tt << 4) + nl] = acc[t][reg];
    }
    __syncthreads();
    float* dst = half ? XR : XL;
#pragma unroll
    for (int i = 0; i < 4; ++i) {
      int idx = (i << 10) + (tid << 2);
      int row = idx >> 6, col = idx & 63;
      *(float4*)(dst + ((m0 + row) << 6) + col) = *(float4*)&cbuf[row * CST + col];
    }
  }
}

// ---------------------------------------------------------------------------
// GATv2 v6 (R15/R16): block = (dst d, graph octet q).
// ---------------------------------------------------------------------------
__global__ __launch_bounds__(256) void k_gat(
    const float* __restrict__ XL, float* __restrict__ XR_HG,
    const float* __restrict__ EPc, const int* __restrict__ offs,
    const int* __restrict__ srcA,
    const float* __restrict__ att, const float* __restrict__ gbl) {
  int d = blockIdx.x;
  int q = blockIdx.y;
  int tid = threadIdx.x;
  int wv = tid >> 6, lane = tid & 63;
  int eSub = lane >> 3, hOct = lane & 7;
  int hb = hOct << 3;
  float at[8], gv[8];
  {
    float4 a0 = *(const float4*)(att + hb);
    float4 a1 = *(const float4*)(att + hb + 4);
    float4 g0v = *(const float4*)(gbl + hb);
    float4 g1v = *(const float4*)(gbl + hb + 4);
    at[0]=a0.x; at[1]=a0.y; at[2]=a0.z; at[3]=a0.w;
    at[4]=a1.x; at[5]=a1.y; at[6]=a1.z; at[7]=a1.w;
    gv[0]=g0v.x; gv[1]=g0v.y; gv[2]=g0v.z; gv[3]=g0v.w;
    gv[4]=g1v.x; gv[5]=g1v.y; gv[6]=g1v.z; gv[7]=g1v.w;
  }
  int p0 = offs[d], p1 = offs[d + 1];
  int nE = p1 - p0;
  int nCh = (nE + 7) >> 3;
  int g0 = (q << 3) + wv;
  int g1 = g0 + 4;
  size_t rowA = ((size_t)(g0 * Nn + d)) << 6;
  size_t rowB = ((size_t)(g1 * Nn + d)) << 6;
  float xrA[8], xrB[8];
  {
    float4 a = *(const float4*)(XR_HG + rowA + hb);
    float4 b = *(const float4*)(XR_HG + rowA + hb + 4);
    float4 c = *(const float4*)(XR_HG + rowB + hb);
    float4 e = *(const float4*)(XR_HG + rowB + hb + 4);
    xrA[0]=a.x; xrA[1]=a.y; xrA[2]=a.z; xrA[3]=a.w; xrA[4]=b.x; xrA[5]=b.y; xrA[6]=b.z; xrA[7]=b.w;
    xrB[0]=c.x; xrB[1]=c.y; xrB[2]=c.z; xrB[3]=c.w; xrB[4]=e.x; xrB[5]=e.y; xrB[6]=e.z; xrB[7]=e.w;
  }
  const float* XA = XL + (((size_t)g0 * Nn) << 6);
  const float* XB = XL + (((size_t)g1 * Nn) << 6);
  float SsA = 0.f, SsB = 0.f;
  float accA[8], accB[8];
#pragma unroll
  for (int j = 0; j < 8; ++j) { accA[j] = 0.f; accB[j] = 0.f; }
  for (int c = 0; c < nCh; ++c) {
    int p = (c << 3) + eSub;
    int pc = p < nE ? p : nE - 1;
    int s = srcA[p0 + pc];
    const float* epp = EPc + (((size_t)(p0 + pc)) << 6) + hb;
    float4 e0 = *(const float4*)epp;
    float4 e1 = *(const float4*)(epp + 4);
    float ep[8] = {e0.x, e0.y, e0.z, e0.w, e1.x, e1.y, e1.z, e1.w};
    const float* xap = XA + ((size_t)s << 6) + hb;
    const float* xbp = XB + ((size_t)s << 6) + hb;
    float4 xa0 = *(const float4*)xap, xa1 = *(const float4*)(xap + 4);
    float4 xb0 = *(const float4*)xbp, xb1 = *(const float4*)(xbp + 4);
    float xA[8] = {xa0.x, xa0.y, xa0.z, xa0.w, xa1.x, xa1.y, xa1.z, xa1.w};
    float xB[8] = {xb0.x, xb0.y, xb0.z, xb0.w, xb1.x, xb1.y, xb1.z, xb1.w};
    float vA = 0.f, vB = 0.f;
#pragma unroll
    for (int j = 0; j < 8; ++j) {
      float mA = xA[j] + xrA[j] + ep[j];
      mA = fmaxf(mA, 0.2f * mA);
      vA = fmaf(mA, at[j], vA);
      float mB = xB[j] + xrB[j] + ep[j];
      mB = fmaxf(mB, 0.2f * mB);
      vB = fmaf(mB, at[j], vB);
    }
    vA = redlogit(vA);
    vB = redlogit(vB);
    float wA = (p < nE) ? __expf(vA) : 0.f;
    float wB = (p < nE) ? __expf(vB) : 0.f;
    SsA += wA; SsB += wB;
#pragma unroll
    for (int j = 0; j < 8; ++j) {
      accA[j] = fmaf(wA, xA[j], accA[j]);
      accB[j] = fmaf(wB, xB[j], accB[j]);
    }
  }
  SsA = red8(SsA); SsB = red8(SsB);
#pragma unroll
  for (int j = 0; j < 8; ++j) { accA[j] = red8(accA[j]); accB[j] = red8(accB[j]); }
  if (eSub == 0) {
    float invA = 1.f / SsA, invB = 1.f / SsB;
    float* opA = XR_HG + rowA + hb;
    float* opB = XR_HG + rowB + hb;
    *(float4*)(opA)     = make_float4(fmaf(accA[0], invA, gv[0]), fmaf(accA[1], invA, gv[1]),
                                      fmaf(accA[2], invA, gv[2]), fmaf(accA[3], invA, gv[3]));
    *(float4*)(opA + 4) = make_float4(fmaf(accA[4], invA, gv[4]), fmaf(accA[5], invA, gv[5]),
                                      fmaf(accA[6], invA, gv[6]), fmaf(accA[7], invA, gv[7]));
    *(float4*)(opB)     = make_float4(fmaf(accB[0], invB, gv[0]), fmaf(accB[1], invB, gv[1]),
                                      fmaf(accB[2], invB, gv[2]), fmaf(accB[3], invB, gv[3]));
    *(float4*)(opB + 4) = make_float4(fmaf(accB[4], invB, gv[4]), fmaf(accB[5], invB, gv[5]),
                                      fmaf(accB[6], invB, gv[6]), fmaf(accB[7], invB, gv[7]));
  }
}

// ---------------------------------------------------------------------------
// Per-t GRU via bf16x3 MFMA, N-split x2: blockIdx.y = h-col half (32 cols).
// 12 acc tiles; staging of hg/hp unchanged (A needs all 64 k). grid (Mm/64,2).
// ---------------------------------------------------------------------------
template <int HASP>
__global__ __launch_bounds__(256) void k_gru_mm(
    const float* __restrict__ hg, const float* __restrict__ hp,
    const unsigned short* __restrict__ WGhi, const unsigned short* __restrict__ WGlo,
    const float* __restrict__ bih, const float* __restrict__ bhh,
    float* __restrict__ hout) {
  __shared__ unsigned short ghi[4096], glo[4096], phi[4096], plo[4096];
  __shared__ float cbuf[64 * GST];
  int tid = threadIdx.x, lane = tid & 63, wv = tid >> 6;
  int ch = blockIdx.y;                      // col half: 0 -> cols 0..31, 1 -> 32..63
  size_t m0 = (size_t)blockIdx.x << 6;
#pragma unroll
  for (int it = 0; it < 2; ++it) {
    int task = (it << 8) + tid;
    int row = task >> 3, cOct = task & 7;
    const float* srcg = hg + ((m0 + row) << 6) + (cOct << 3);
    float4 a = *(const float4*)srcg;
    float4 b = *(const float4*)(srcg + 4);
    float va[8] = {a.x, a.y, a.z, a.w, b.x, b.y, b.z, b.w};
    short8 hv, lv;
#pragma unroll
    for (int j = 0; j < 8; ++j) {
      unsigned short hs, ls;
      split_bf16(va[j], hs, ls);
      hv[j] = (short)hs; lv[j] = (short)ls;
    }
    int f = ((cOct >> 2) * 4 + (row >> 4)) * 64 + ((cOct & 3) << 4) + (row & 15);
    *(short8*)&ghi[f << 3] = hv;
    *(short8*)&glo[f << 3] = lv;
    if (HASP) {
      const float* srcp = hp + ((m0 + row) << 6) + (cOct << 3);
      float4 c = *(const float4*)srcp;
      float4 e = *(const float4*)(srcp + 4);
      float vp[8] = {c.x, c.y, c.z, c.w, e.x, e.y, e.z, e.w};
#pragma unroll
      for (int j = 0; j < 8; ++j) {
        unsigned short hs, ls;
        split_bf16(vp[j], hs, ls);
        hv[j] = (short)hs; lv[j] = (short)ls;
      }
      *(short8*)&phi[f << 3] = hv;
      *(short8*)&plo[f << 3] = lv;
    }
  }
  __syncthreads();
  short8 Gh0 = *(const short8*)&ghi[((0 + wv) << 6 | lane) << 3];
  short8 Gl0 = *(const short8*)&glo[((0 + wv) << 6 | lane) << 3];
  short8 Gh1 = *(const short8*)&ghi[((4 + wv) << 6 | lane) << 3];
  short8 Gl1 = *(const short8*)&glo[((4 + wv) << 6 | lane) << 3];
  short8 Ph0, Pl0, Ph1, Pl1;
  if (HASP) {
    Ph0 = *(const short8*)&phi[((0 + wv) << 6 | lane) << 3];
    Pl0 = *(const short8*)&plo[((0 + wv) << 6 | lane) << 3];
    Ph1 = *(const short8*)&phi[((4 + wv) << 6 | lane) << 3];
    Pl1 = *(const short8*)&plo[((4 + wv) << 6 | lane) << 3];
  }
  int nl = lane & 15;
  // local tiles: g in 0..5 (r_i,z_i,n_i,r_h,z_h,n_h), ct2 in 0..1
  f32x4 acc[12];
#pragma unroll
  for (int g = 0; g < 6; ++g)
#pragma unroll
    for (int ct2 = 0; ct2 < 2; ++ct2) {
      int c = (((ch << 1) + ct2) << 4) + nl;
      float b = (g < 3) ? bih[(g << 6) + c] : bhh[((g - 3) << 6) + c];
      acc[(g << 1) + ct2] = (f32x4){b, b, b, b};
    }
#pragma unroll
  for (int g = 0; g < 3; ++g)
#pragma unroll
    for (int ct2 = 0; ct2 < 2; ++ct2) {
      int t = (g << 2) + (ch << 1) + ct2;   // global tile index (ih)
      const short8* bh0p = (const short8*)(WGhi + ((t << 1) << 9)) + lane;
      const short8* bl0p = (const short8*)(WGlo + ((t << 1) << 9)) + lane;
      const short8* bh1p = (const short8*)(WGhi + (((t << 1) + 1) << 9)) + lane;
      const short8* bl1p = (const short8*)(WGlo + (((t << 1) + 1) << 9)) + lane;
      short8 bh0 = *bh0p, bl0 = *bl0p, bh1 = *bh1p, bl1 = *bl1p;
      int a = (g << 1) + ct2;
      acc[a] = MFMA16(Gh0, bh0, acc[a], 0, 0, 0);
      acc[a] = MFMA16(Gh0, bl0, acc[a], 0, 0, 0);
      acc[a] = MFMA16(Gl0, bh0, acc[a], 0, 0, 0);
      acc[a] = MFMA16(Gh1, bh1, acc[a], 0, 0, 0);
      acc[a] = MFMA16(Gh1, bl1, acc[a], 0, 0, 0);
      acc[a] = MFMA16(Gl1, bh1, acc[a], 0, 0, 0);
    }
  if (HASP) {
#pragma unroll
    for (int g = 0; g < 3; ++g)
#pragma unroll
      for (int ct2 = 0; ct2 < 2; ++ct2) {
        int t = 12 + (g << 2) + (ch << 1) + ct2;  // global tile index (hh)
        const short8* bh0p = (const short8*)(WGhi + ((t << 1) << 9)) + lane;
        const short8* bl0p = (const short8*)(WGlo + ((t << 1) << 9)) + lane;
        const short8* bh1p = (const short8*)(WGhi + (((t << 1) + 1) << 9)) + lane;
        const short8* bl1p = (const short8*)(WGlo + (((t << 1) + 1) << 9)) + lane;
        short8 bh0 = *bh0p, bl0 = *bl0p, bh1 = *bh1p, bl1 = *bl1p;
        int a = 6 + (g << 1) + ct2;
        acc[a] = MFMA16(Ph0, bh0, acc[a], 0, 0, 0);
        acc[a] = MFMA16(Ph0, bl0, acc[a], 0, 0, 0);
        acc[a] = MFMA16(Pl0, bh0, acc[a], 0, 0, 0);
        acc[a] = MFMA16(Ph1, bh1, acc[a], 0, 0, 0);
        acc[a] = MFMA16(Ph1, bl1, acc[a], 0, 0, 0);
        acc[a] = MFMA16(Pl1, bh1, acc[a], 0, 0, 0);
      }
  }
  int rbase = (wv << 4) + ((lane >> 4) << 2);
#pragma unroll
  for (int ct2 = 0; ct2 < 2; ++ct2) {
    int c = (((ch << 1) + ct2) << 4) + nl;      // global col
    int cl = (ct2 << 4) + nl;                   // local col (0..31)
#pragma unroll
    for (int reg = 0; reg < 4; ++reg) {
      size_t rowg = m0 + rbase + reg;
      float rg = sigf(acc[ct2][reg]      + acc[6 + ct2][reg]);
      float zg = sigf(acc[2 + ct2][reg]  + acc[8 + ct2][reg]);
      float ng = tanhfast(acc[4 + ct2][reg] + rg * acc[10 + ct2][reg]);
      float hv = HASP ? hp[(rowg << 6) + c] : 0.f;
      cbuf[(rbase + reg) * GST + cl] = (1.f - zg) * ng + zg * hv;
    }
  }
  __syncthreads();
#pragma unroll
  for (int i = 0; i < 2; ++i) {
    int idx = (i << 10) + (tid << 2);           // 0..2047
    int row = idx >> 5, col = idx & 31;
    *(float4*)(hout + ((m0 + row) << 6) + (ch << 5) + col) = *(float4*)&cbuf[row * GST + col];
  }
}

// ---------------------------------------------------------------------------
// Heads v2 (R17, measured good).
// ---------------------------------------------------------------------------
__global__ __launch_bounds__(256) void k_heads(
    const float* __restrict__ Xb,
    const float* __restrict__ oW1, const float* __restrict__ ob1,
    const float* __restrict__ oW2, const float* __restrict__ ob2,
    const float* __restrict__ dW1, const float* __restrict__ db1,
    const float* __restrict__ dW2, const float* __restrict__ db2,
    float* __restrict__ out) {
  __shared__ float xa[64 * 65];
  __shared__ float w1o[64 * 32], w1d[64 * 32];
  __shared__ float po[4][64], pd[4][64];
  int tid = threadIdx.x;
  int rblk = blockIdx.x << 6;
  int b = rblk >> 11;
  int n0 = rblk & (Nn - 1);
  const float* src = Xb + (((size_t)b * Ss + (Ss - 1)) * Nn + n0) * Hh;
#pragma unroll
  for (int i = 0; i < 4; ++i) {
    int idx = (i << 10) + (tid << 2);
    int row = idx >> 6, col = idx & 63;
    float4 v = *(const float4*)(src + idx);
    float* dp = &xa[row * 65 + col];
    dp[0] = v.x; dp[1] = v.y; dp[2] = v.z; dp[3] = v.w;
  }
  for (int idx = tid; idx < 2048; idx += 256) {
    w1o[idx] = oW1[idx];
    w1d[idx] = dW1[idx];
  }
  __syncthreads();
  int row = tid & 63;
  int jg = tid >> 6;
  int j0 = jg << 3;
  float hO[8], hD[8];
#pragma unroll
  for (int j = 0; j < 8; ++j) { hO[j] = ob1[j0 + j]; hD[j] = db1[j0 + j]; }
  const float* xr = &xa[row * 65];
  for (int k = 0; k < 64; ++k) {
    float xv = xr[k];
    const float4* wo = (const float4*)&w1o[(k << 5) + j0];
    const float4* wd = (const float4*)&w1d[(k << 5) + j0];
    float4 o0 = wo[0], o1 = wo[1], d0 = wd[0], d1 = wd[1];
    hO[0] = fmaf(xv, o0.x, hO[0]); hO[1] = fmaf(xv, o0.y, hO[1]);
    hO[2] = fmaf(xv, o0.z, hO[2]); hO[3] = fmaf(xv, o0.w, hO[3]);
    hO[4] = fmaf(xv, o1.x, hO[4]); hO[5] = fmaf(xv, o1.y, hO[5]);
    hO[6] = fmaf(xv, o1.z, hO[6]); hO[7] = fmaf(xv, o1.w, hO[7]);
    hD[0] = fmaf(xv, d0.x, hD[0]); hD[1] = fmaf(xv, d0.y, hD[1]);
    hD[2] = fmaf(xv, d0.z, hD[2]); hD[3] = fmaf(xv, d0.w, hD[3]);
    hD[4] = fmaf(xv, d1.x, hD[4]); hD[5] = fmaf(xv, d1.y, hD[5]);
    hD[6] = fmaf(xv, d1.z, hD[6]); hD[7] = fmaf(xv, d1.w, hD[7]);
  }
  float accoP = 0.f, accdP = 0.f;
#pragma unroll
  for (int j = 0; j < 8; ++j) {
    accoP = fmaf(fmaxf(hO[j], 0.f), oW2[j0 + j], accoP);
    accdP = fmaf(fmaxf(hD[j], 0.f), dW2[j0 + j], accdP);
  }
  po[jg][row] = accoP;
  pd[jg][row] = accdP;
  __syncthreads();
  if (tid < 64) {
    int r = rblk + tid;
    out[r]           = ob2[0] + ((po[0][tid] + po[1][tid]) + (po[2][tid] + po[3][tid]));
    out[Bb * Nn + r] = db2[0] + ((pd[0][tid] + pd[1][tid]) + (pd[2][tid] + pd[3][tid]));
  }
}

// ---------------------------------------------------------------------------
extern "C" void kernel_launch(void* const* d_in, const int* in_sizes, int n_in,
                              void* d_out, int out_size, void* d_ws, size_t ws_size,
                              hipStream_t stream) {
  const float* x   = (const float*)d_in[0];
  const int*   ei  = (const int*)d_in[1];
  const float* ea  = (const float*)d_in[2];
  const float* Wp  = (const float*)d_in[3];
  const float* bp  = (const float*)d_in[4];
  const float* Wl  = (const float*)d_in[5];
  const float* bl  = (const float*)d_in[6];
  const float* Wr  = (const float*)d_in[7];
  const float* br  = (const float*)d_in[8];
  const float* We  = (const float*)d_in[9];
  const float* att = (const float*)d_in[10];
  const float* gb  = (const float*)d_in[11];
  const float* Wih = (const float*)d_in[12];
  const float* Whh = (const float*)d_in[13];
  const float* bih = (const float*)d_in[14];
  const float* bhh = (const float*)d_in[15];
  const float* oW1 = (const float*)d_in[16];
  const float* ob1 = (const float*)d_in[17];
  const float* oW2 = (const float*)d_in[18];
  const float* ob2 = (const float*)d_in[19];
  const float* dW1 = (const float*)d_in[20];
  const float* db1 = (const float*)d_in[21];
  const float* dW2 = (const float*)d_in[22];
  const float* db2 = (const float*)d_in[23];
  float* out = (float*)d_out;

  // workspace layout
  float* f    = (float*)d_ws;
  float* Xb   = f;                          // RTOT*64
  float* XLb  = Xb  + (size_t)RTOT * Hh;
  float* XRb  = XLb + (size_t)RTOT * Hh;    // hg after k_gat
  float* EPc  = XRb + (size_t)RTOT * Hh;    // 2 * E2c * 64 (CSR order, both layers)
  unsigned short* WXhi = (unsigned short*)(EPc + (size_t)2 * E2c * Hh); // 16384
  unsigned short* WXlo = WXhi + 16384;
  unsigned short* WGhi = WXlo + 16384;      // 49152
  unsigned short* WGlo = WGhi + 49152;
  float* cntF = (float*)(WGlo + 49152);     // 2048
  float* loopA = cntF + Nn;                 // 2048*8
  int*   fillI = (int*)(loopA + Nn * EFf);  // 2048
  int*   offs  = fillI + Nn;                // 2049 (+pad)
  int*   posOf = offs + 2052;               // 18432
  int*   srcA  = posOf + E2c;               // 18432

  hipMemsetAsync(cntF, 0, (size_t)(Nn + Nn * EFf + Nn) * 4, stream);

  k_loop_accum<<<dim3(Ee * EFf / 256), 256, 0, stream>>>(ei, ea, cntF, loopA);
  k_scan<<<1, 256, 0, stream>>>(cntF, offs);
  k_scatter<<<dim3((E2c + 255) / 256), 256, 0, stream>>>(ei, offs, fillI, posOf, srcA);
  k_wprep<<<dim3(256), 256, 0, stream>>>(Wl, Wr, Wih, Whh, WXhi, WXlo, WGhi, WGlo);

  // X = x @ Wp + bp
  k_proj<<<dim3(RTOT / 512, 4), 256, 0, stream>>>(x, Wp, bp, Xb);

  // ep for both layers (division by cnt folded in)
  k_ep<<<dim3(E2c * Hh / 256, 2), 256, 0, stream>>>(ea, loopA, We, posOf, cntF, EPc);

  for (int l = 0; l < 2; ++l) {
    k_xlr_mm<<<dim3(RTOT / 64), 256, 0, stream>>>(
        Xb, WXhi + (size_t)l * 8192, WXlo + (size_t)l * 8192,
        bl + (size_t)l * Hh, br + (size_t)l * Hh, XLb, XRb);
    k_gat<<<dim3(Nn, 8), 256, 0, stream>>>(
        XLb, XRb, EPc + (size_t)l * E2c * Hh, offs, srcA,
        att + (size_t)l * Hh, gb + (size_t)l * Hh);
    const unsigned short* WGh_l = WGhi + (size_t)l * 24576;
    const unsigned short* WGl_l = WGlo + (size_t)l * 24576;
    const float* bih_l = bih + (size_t)l * 192;
    const float* bhh_l = bhh + (size_t)l * 192;
    for (int t = 0; t < Bb; ++t) {
      const float* hg_t = XRb + (size_t)t * Mm * Hh;
      float* h_out = Xb + (size_t)t * Mm * Hh;
      if (t == 0) {
        k_gru_mm<0><<<dim3(Mm / 64, 2), 256, 0, stream>>>(
            hg_t, nullptr, WGh_l, WGl_l, bih_l, bhh_l, h_out);
      } else {
        const float* h_prev = Xb + (size_t)(t - 1) * Mm * Hh;
        k_gru_mm<1><<<dim3(Mm / 64, 2), 256, 0, stream>>>(
            hg_t, h_prev, WGh_l, WGl_l, bih_l, bhh_l, h_out);
      }
    }
  }

  k_heads<<<dim3(Bb * Nn / 64), 256, 0, stream>>>(
      Xb, oW1, ob1, oW2, ob2, dW1, db1, dW2, db2, out);
}

// Round 20
// 418.502 us; speedup vs baseline: 1.3780x; 1.0083x over previous
//
#include <hip/hip_runtime.h>
#include <math.h>

#define Bb   4
#define Ss   16
#define Nn   2048
#define Ff   32
#define Ee   16384
#define EFf  8
#define Hh   64
#define HB2  32
#define E2c  (Ee + Nn)          // 18432
#define RTOT (Bb*Ss*Nn)         // 131072 (64 graphs x 2048)
#define Mm   (Ss*Nn)            // 32768
#define CST  68                 // xlr cbuf row stride
#define GST  36                 // gru cbuf row stride (32 cols + pad)

typedef __attribute__((ext_vector_type(8))) short short8;
typedef __attribute__((ext_vector_type(4))) float f32x4;
#define MFMA16 __builtin_amdgcn_mfma_f32_16x16x32_bf16

__device__ __forceinline__ float sigf(float x) { return 1.f / (1.f + __expf(-x)); }
__device__ __forceinline__ float tanhfast(float x) { return 2.f / (1.f + __expf(-2.f * x)) - 1.f; }

__device__ __forceinline__ void split_bf16(float x, unsigned short& h, unsigned short& l) {
  unsigned u = __float_as_uint(x);
  unsigned r = (u + 0x7FFFu + ((u >> 16) & 1u)) >> 16;
  h = (unsigned short)r;
  float rest = x - __uint_as_float(r << 16);
  unsigned u2 = __float_as_uint(rest);
  l = (unsigned short)((u2 + 0x7FFFu + ((u2 >> 16) & 1u)) >> 16);
}

template <int PAT>
__device__ __forceinline__ float xorf(float v) {
  return __int_as_float(__builtin_amdgcn_ds_swizzle(__float_as_int(v), PAT));
}
__device__ __forceinline__ float red8(float v) {
  int x = __builtin_amdgcn_update_dpp(0, __float_as_int(v), 0x128, 0xF, 0xF, true);
  v += __int_as_float(x);
  v += xorf<0x401F>(v);
  v += __shfl_xor(v, 32, 64);
  return v;
}
__device__ __forceinline__ float redlogit(float v) {
  int x;
  x = __builtin_amdgcn_update_dpp(0, __float_as_int(v), 0xB1, 0xF, 0xF, true);
  v += __int_as_float(x);
  x = __builtin_amdgcn_update_dpp(0, __float_as_int(v), 0x4E, 0xF, 0xF, true);
  v += __int_as_float(x);
  v += xorf<0x101F>(v);
  return v;
}

// ---------------------------------------------------------------------------
__global__ __launch_bounds__(256) void k_loop_accum(
    const int* __restrict__ ei, const float* __restrict__ ea,
    float* __restrict__ cntF, float* __restrict__ loopA) {
  int idx = blockIdx.x * 256 + threadIdx.x;
  int e = idx >> 3, j = idx & 7;
  int d = ei[Ee + e];
  atomicAdd(&loopA[d * EFf + j], ea[idx]);
  if (j == 0) atomicAdd(&cntF[d], 1.0f);
}

// ---------------------------------------------------------------------------
__global__ __launch_bounds__(256) void k_scan(
    const float* __restrict__ cntF, int* __restrict__ offs) {
  __shared__ int partial[256];
  int tid = threadIdx.x;
  int base = tid * 8;
  int vals[8];
  int s = 0;
  for (int i = 0; i < 8; ++i) {
    int c = (int)cntF[base + i] + 1;
    vals[i] = c;
    s += c;
  }
  partial[tid] = s;
  __syncthreads();
  for (int off = 1; off < 256; off <<= 1) {
    int v = partial[tid];
    int add = (tid >= off) ? partial[tid - off] : 0;
    __syncthreads();
    partial[tid] = v + add;
    __syncthreads();
  }
  int run = (tid == 0) ? 0 : partial[tid - 1];
  for (int i = 0; i < 8; ++i) {
    offs[base + i] = run;
    run += vals[i];
  }
  if (tid == 255) offs[Nn] = run;
}

__global__ __launch_bounds__(256) void k_scatter(
    const int* __restrict__ ei, const int* __restrict__ offs,
    int* __restrict__ fillI, int* __restrict__ posOf, int* __restrict__ srcA) {
  int e = blockIdx.x * 256 + threadIdx.x;
  if (e >= E2c) return;
  int d = (e < Ee) ? ei[Ee + e] : (e - Ee);
  int s = (e < Ee) ? ei[e]      : (e - Ee);
  int pos = offs[d] + atomicAdd(&fillI[d], 1);
  posOf[e] = pos;
  srcA[pos] = s;
}

// ---------------------------------------------------------------------------
// Pre-split + pre-swizzle weights into MFMA B-fragment order (R9 layout).
// ---------------------------------------------------------------------------
__global__ __launch_bounds__(256) void k_wprep(
    const float* __restrict__ Wl, const float* __restrict__ Wr,
    const float* __restrict__ Wih, const float* __restrict__ Whh,
    unsigned short* __restrict__ WXhi, unsigned short* __restrict__ WXlo,
    unsigned short* __restrict__ WGhi, unsigned short* __restrict__ WGlo) {
  int idx = blockIdx.x * 256 + threadIdx.x;   // 65536 total
  if (idx < 16384) {
    int j = idx & 7, lane = (idx >> 3) & 63, kh = (idx >> 9) & 1;
    int t = (idx >> 10) & 7, l = idx >> 13;
    int n = t * 16 + (lane & 15);
    int k = kh * 32 + ((lane >> 4) << 3) + j;
    const float* W = (n < 64) ? (Wl + (size_t)l * 4096) : (Wr + (size_t)l * 4096);
    float v = W[k * 64 + (n & 63)];
    unsigned short h, lo;
    split_bf16(v, h, lo);
    WXhi[idx] = h; WXlo[idx] = lo;
  } else {
    int i2 = idx - 16384;                     // < 49152
    int j = i2 & 7, lane = (i2 >> 3) & 63, kh = (i2 >> 9) & 1;
    int t = (i2 >> 10) % 24, l = i2 / 24576;
    int n = t * 16 + (lane & 15);
    int k = kh * 32 + ((lane >> 4) << 3) + j;
    int g = n >> 6, c = n & 63;
    const float* W = (g < 3) ? (Wih + (size_t)l * 12288 + (size_t)(g * 64 + c) * 64)
                             : (Whh + (size_t)l * 12288 + (size_t)((g - 3) * 64 + c) * 64);
    float v = W[k];
    unsigned short h, lo;
    split_bf16(v, h, lo);
    WGhi[i2] = h; WGlo[i2] = lo;
  }
}

// ---------------------------------------------------------------------------
// ep for BOTH layers; self-loop mean division folded in. blockIdx.y = layer.
// ---------------------------------------------------------------------------
__global__ __launch_bounds__(256) void k_ep(
    const float* __restrict__ ea, const float* __restrict__ loopA,
    const float* __restrict__ We, const int* __restrict__ posOf,
    const float* __restrict__ cntF, float* __restrict__ EPc) {
  __shared__ float wlds[EFf * Hh];
  int tid = threadIdx.x;
  int l = blockIdx.y;
  const float* Wel = We + (size_t)l * EFf * Hh;
  if (tid < EFf * Hh) wlds[tid] = Wel[tid];
  if (tid + 256 < EFf * Hh) wlds[tid + 256] = Wel[tid + 256];
  __syncthreads();
  int idx = blockIdx.x * 256 + tid;
  int e = idx >> 6, j = idx & 63;
  const float* a = (e < Ee) ? (ea + (size_t)e * EFf) : (loopA + (size_t)(e - Ee) * EFf);
  float acc = 0.f;
#pragma unroll
  for (int k = 0; k < EFf; ++k) acc += a[k] * wlds[k * Hh + j];
  if (e >= Ee) acc /= fmaxf(cntF[e - Ee], 1.0f);
  EPc[(size_t)l * E2c * Hh + (((size_t)posOf[e]) << 6) + j] = acc;
}

// ---------------------------------------------------------------------------
// proj (R5 version): thread = 2 rows x 16 cols. grid (RTOT/512, 4)
// ---------------------------------------------------------------------------
__global__ __launch_bounds__(256) void k_proj(
    const float* __restrict__ X, const float* __restrict__ Wp,
    const float* __restrict__ bp, float* __restrict__ Out) {
  __shared__ float w[32 * 16];
  int tid = threadIdx.x;
  int j0 = blockIdx.y << 4;
  for (int idx = tid; idx < 32 * 16; idx += 256)
    w[idx] = Wp[((idx >> 4) << 6) + j0 + (idx & 15)];
  __syncthreads();
  int r0 = (blockIdx.x << 9) + tid;
  float acc[2][16];
#pragma unroll
  for (int jj = 0; jj < 16; ++jj) { float b = bp[j0 + jj]; acc[0][jj] = b; acc[1][jj] = b; }
  const float* x0 = X + ((size_t)r0 << 5);
  const float* x1 = x0 + (256 << 5);
  for (int kc = 0; kc < 8; ++kc) {
    float4 a0 = *(const float4*)(x0 + 4 * kc);
    float4 a1 = *(const float4*)(x1 + 4 * kc);
    float a0a[4] = {a0.x, a0.y, a0.z, a0.w};
    float a1a[4] = {a1.x, a1.y, a1.z, a1.w};
#pragma unroll
    for (int q = 0; q < 4; ++q) {
      const float4* wp4 = (const float4*)(w + ((4 * kc + q) << 4));
#pragma unroll
      for (int q4 = 0; q4 < 4; ++q4) {
        float4 wv = wp4[q4];
        acc[0][4*q4+0] = fmaf(a0a[q], wv.x, acc[0][4*q4+0]);
        acc[0][4*q4+1] = fmaf(a0a[q], wv.y, acc[0][4*q4+1]);
        acc[0][4*q4+2] = fmaf(a0a[q], wv.z, acc[0][4*q4+2]);
        acc[0][4*q4+3] = fmaf(a0a[q], wv.w, acc[0][4*q4+3]);
        acc[1][4*q4+0] = fmaf(a1a[q], wv.x, acc[1][4*q4+0]);
        acc[1][4*q4+1] = fmaf(a1a[q], wv.y, acc[1][4*q4+1]);
        acc[1][4*q4+2] = fmaf(a1a[q], wv.z, acc[1][4*q4+2]);
        acc[1][4*q4+3] = fmaf(a1a[q], wv.w, acc[1][4*q4+3]);
      }
    }
  }
#pragma unroll
  for (int rr = 0; rr < 2; ++rr) {
    float* op = Out + (((size_t)(r0 + 256 * rr)) << 6) + j0;
#pragma unroll
    for (int q4 = 0; q4 < 4; ++q4)
      *(float4*)(op + 4 * q4) = make_float4(acc[rr][4*q4], acc[rr][4*q4+1], acc[rr][4*q4+2], acc[rr][4*q4+3]);
  }
}

// ---------------------------------------------------------------------------
// XL/XR via bf16x3 MFMA (R14, measured good).
// ---------------------------------------------------------------------------
__global__ __launch_bounds__(256) void k_xlr_mm(
    const float* __restrict__ X,
    const unsigned short* __restrict__ WXhi, const unsigned short* __restrict__ WXlo,
    const float* __restrict__ bl_, const float* __restrict__ br_,
    float* __restrict__ XL, float* __restrict__ XR) {
  __shared__ unsigned short ahi[4096], alo[4096];
  __shared__ float cbuf[64 * CST];
  int tid = threadIdx.x, lane = tid & 63, wv = tid >> 6;
  size_t m0 = (size_t)blockIdx.x << 6;
#pragma unroll
  for (int it = 0; it < 2; ++it) {
    int task = (it << 8) + tid;
    int row = task >> 3, cOct = task & 7;
    const float* src = X + ((m0 + row) << 6) + (cOct << 3);
    float4 a = *(const float4*)src;
    float4 b = *(const float4*)(src + 4);
    float va[8] = {a.x, a.y, a.z, a.w, b.x, b.y, b.z, b.w};
    short8 hv, lv;
#pragma unroll
    for (int j = 0; j < 8; ++j) {
      unsigned short hs, ls;
      split_bf16(va[j], hs, ls);
      hv[j] = (short)hs; lv[j] = (short)ls;
    }
    int f = ((cOct >> 2) * 4 + (row >> 4)) * 64 + ((cOct & 3) << 4) + (row & 15);
    *(short8*)&ahi[f << 3] = hv;
    *(short8*)&alo[f << 3] = lv;
  }
  __syncthreads();
  short8 Ah0 = *(const short8*)&ahi[((0 + wv) << 6 | lane) << 3];
  short8 Al0 = *(const short8*)&alo[((0 + wv) << 6 | lane) << 3];
  short8 Ah1 = *(const short8*)&ahi[((4 + wv) << 6 | lane) << 3];
  short8 Al1 = *(const short8*)&alo[((4 + wv) << 6 | lane) << 3];
  int nl = lane & 15;
  f32x4 acc[8];
#pragma unroll
  for (int t = 0; t < 8; ++t) {
    int n = t * 16 + nl;
    float b = (n < 64) ? bl_[n] : br_[n - 64];
    acc[t] = (f32x4){b, b, b, b};
  }
#pragma unroll
  for (int t = 0; t < 8; ++t) {
    const short8* bh0p = (const short8*)(WXhi + ((t << 1) << 9)) + lane;
    const short8* bl0p = (const short8*)(WXlo + ((t << 1) << 9)) + lane;
    const short8* bh1p = (const short8*)(WXhi + (((t << 1) + 1) << 9)) + lane;
    const short8* bl1p = (const short8*)(WXlo + (((t << 1) + 1) << 9)) + lane;
    short8 bh0 = *bh0p, bl0 = *bl0p, bh1 = *bh1p, bl1 = *bl1p;
    acc[t] = MFMA16(Ah0, bh0, acc[t], 0, 0, 0);
    acc[t] = MFMA16(Ah0, bl0, acc[t], 0, 0, 0);
    acc[t] = MFMA16(Al0, bh0, acc[t], 0, 0, 0);
    acc[t] = MFMA16(Ah1, bh1, acc[t], 0, 0, 0);
    acc[t] = MFMA16(Ah1, bl1, acc[t], 0, 0, 0);
    acc[t] = MFMA16(Al1, bh1, acc[t], 0, 0, 0);
  }
  int rbase = (wv << 4) + ((lane >> 4) << 2);
#pragma unroll
  for (int half = 0; half < 2; ++half) {
    __syncthreads();
#pragma unroll
    for (int tt = 0; tt < 4; ++tt) {
      int t = (half << 2) + tt;
#pragma unroll
      for (int reg = 0; reg < 4; ++reg)
        cbuf[(rbase + reg) * CST + (tt << 4) + nl] = acc[t][reg];
    }
    __syncthreads();
    float* dst = half ? XR : XL;
#pragma unroll
    for (int i = 0; i < 4; ++i) {
      int idx = (i << 10) + (tid << 2);
      int row = idx >> 6, col = idx & 63;
      *(float4*)(dst + ((m0 + row) << 6) + col) = *(float4*)&cbuf[row * CST + col];
    }
  }
}

// ---------------------------------------------------------------------------
// GATv2 v7: block = (dst d, graph 16-group q). Wave handles 4 graphs
// (q*16+wv+4c). EP/srcA loads amortized over 4 chains; ~10 VMEM in flight.
// grid (Nn, 4).
// ---------------------------------------------------------------------------
__global__ __launch_bounds__(256) void k_gat(
    const float* __restrict__ XL, float* __restrict__ XR_HG,
    const float* __restrict__ EPc, const int* __restrict__ offs,
    const int* __restrict__ srcA,
    const float* __restrict__ att, const float* __restrict__ gbl) {
  int d = blockIdx.x;
  int q = blockIdx.y;
  int tid = threadIdx.x;
  int wv = tid >> 6, lane = tid & 63;
  int eSub = lane >> 3, hOct = lane & 7;
  int hb = hOct << 3;
  float at[8], gv[8];
  {
    float4 a0 = *(const float4*)(att + hb);
    float4 a1 = *(const float4*)(att + hb + 4);
    float4 g0v = *(const float4*)(gbl + hb);
    float4 g1v = *(const float4*)(gbl + hb + 4);
    at[0]=a0.x; at[1]=a0.y; at[2]=a0.z; at[3]=a0.w;
    at[4]=a1.x; at[5]=a1.y; at[6]=a1.z; at[7]=a1.w;
    gv[0]=g0v.x; gv[1]=g0v.y; gv[2]=g0v.z; gv[3]=g0v.w;
    gv[4]=g1v.x; gv[5]=g1v.y; gv[6]=g1v.z; gv[7]=g1v.w;
  }
  int p0 = offs[d], p1 = offs[d + 1];
  int nE = p1 - p0;
  int nCh = (nE + 7) >> 3;
  int gbase = (q << 4) + wv;
  size_t rowg[4];
  const float* Xg[4];
  float xr[4][8];
#pragma unroll
  for (int c = 0; c < 4; ++c) {
    int g = gbase + (c << 2);
    rowg[c] = ((size_t)(g * Nn + d)) << 6;
    Xg[c] = XL + (((size_t)g * Nn) << 6);
    float4 a = *(const float4*)(XR_HG + rowg[c] + hb);
    float4 b = *(const float4*)(XR_HG + rowg[c] + hb + 4);
    xr[c][0]=a.x; xr[c][1]=a.y; xr[c][2]=a.z; xr[c][3]=a.w;
    xr[c][4]=b.x; xr[c][5]=b.y; xr[c][6]=b.z; xr[c][7]=b.w;
  }
  float Sd[4] = {0.f, 0.f, 0.f, 0.f};
  float acc[4][8];
#pragma unroll
  for (int c = 0; c < 4; ++c)
#pragma unroll
    for (int j = 0; j < 8; ++j) acc[c][j] = 0.f;

  for (int ck = 0; ck < nCh; ++ck) {
    int p = (ck << 3) + eSub;
    int pc = p < nE ? p : nE - 1;
    int s = srcA[p0 + pc];
    const float* epp = EPc + (((size_t)(p0 + pc)) << 6) + hb;
    float4 e0 = *(const float4*)epp;
    float4 e1 = *(const float4*)(epp + 4);
    float ep[8] = {e0.x, e0.y, e0.z, e0.w, e1.x, e1.y, e1.z, e1.w};
    float xlv[4][8];
#pragma unroll
    for (int c = 0; c < 4; ++c) {
      const float* xp = Xg[c] + ((size_t)s << 6) + hb;
      float4 x0 = *(const float4*)xp;
      float4 x1 = *(const float4*)(xp + 4);
      xlv[c][0]=x0.x; xlv[c][1]=x0.y; xlv[c][2]=x0.z; xlv[c][3]=x0.w;
      xlv[c][4]=x1.x; xlv[c][5]=x1.y; xlv[c][6]=x1.z; xlv[c][7]=x1.w;
    }
    float v[4] = {0.f, 0.f, 0.f, 0.f};
#pragma unroll
    for (int c = 0; c < 4; ++c)
#pragma unroll
      for (int j = 0; j < 8; ++j) {
        float m = xlv[c][j] + xr[c][j] + ep[j];
        m = fmaxf(m, 0.2f * m);
        v[c] = fmaf(m, at[j], v[c]);
      }
#pragma unroll
    for (int c = 0; c < 4; ++c) v[c] = redlogit(v[c]);
    bool live = (p < nE);
#pragma unroll
    for (int c = 0; c < 4; ++c) {
      float w = live ? __expf(v[c]) : 0.f;
      Sd[c] += w;
#pragma unroll
      for (int j = 0; j < 8; ++j) acc[c][j] = fmaf(w, xlv[c][j], acc[c][j]);
    }
  }
#pragma unroll
  for (int c = 0; c < 4; ++c) {
    Sd[c] = red8(Sd[c]);
#pragma unroll
    for (int j = 0; j < 8; ++j) acc[c][j] = red8(acc[c][j]);
  }
  if (eSub == 0) {
#pragma unroll
    for (int c = 0; c < 4; ++c) {
      float inv = 1.f / Sd[c];
      float* op = XR_HG + rowg[c] + hb;
      *(float4*)(op)     = make_float4(fmaf(acc[c][0], inv, gv[0]), fmaf(acc[c][1], inv, gv[1]),
                                       fmaf(acc[c][2], inv, gv[2]), fmaf(acc[c][3], inv, gv[3]));
      *(float4*)(op + 4) = make_float4(fmaf(acc[c][4], inv, gv[4]), fmaf(acc[c][5], inv, gv[5]),
                                       fmaf(acc[c][6], inv, gv[6]), fmaf(acc[c][7], inv, gv[7]));
    }
  }
}

// ---------------------------------------------------------------------------
// Per-t GRU via bf16x3 MFMA, N-split x2 (R18).
// ---------------------------------------------------------------------------
template <int HASP>
__global__ __launch_bounds__(256) void k_gru_mm(
    const float* __restrict__ hg, const float* __restrict__ hp,
    const unsigned short* __restrict__ WGhi, const unsigned short* __restrict__ WGlo,
    const float* __restrict__ bih, const float* __restrict__ bhh,
    float* __restrict__ hout) {
  __shared__ unsigned short ghi[4096], glo[4096], phi[4096], plo[4096];
  __shared__ float cbuf[64 * GST];
  int tid = threadIdx.x, lane = tid & 63, wv = tid >> 6;
  int ch = blockIdx.y;
  size_t m0 = (size_t)blockIdx.x << 6;
#pragma unroll
  for (int it = 0; it < 2; ++it) {
    int task = (it << 8) + tid;
    int row = task >> 3, cOct = task & 7;
    const float* srcg = hg + ((m0 + row) << 6) + (cOct << 3);
    float4 a = *(const float4*)srcg;
    float4 b = *(const float4*)(srcg + 4);
    float va[8] = {a.x, a.y, a.z, a.w, b.x, b.y, b.z, b.w};
    short8 hv, lv;
#pragma unroll
    for (int j = 0; j < 8; ++j) {
      unsigned short hs, ls;
      split_bf16(va[j], hs, ls);
      hv[j] = (short)hs; lv[j] = (short)ls;
    }
    int f = ((cOct >> 2) * 4 + (row >> 4)) * 64 + ((cOct & 3) << 4) + (row & 15);
    *(short8*)&ghi[f << 3] = hv;
    *(short8*)&glo[f << 3] = lv;
    if (HASP) {
      const float* srcp = hp + ((m0 + row) << 6) + (cOct << 3);
      float4 c = *(const float4*)srcp;
      float4 e = *(const float4*)(srcp + 4);
      float vp[8] = {c.x, c.y, c.z, c.w, e.x, e.y, e.z, e.w};
#pragma unroll
      for (int j = 0; j < 8; ++j) {
        unsigned short hs, ls;
        split_bf16(vp[j], hs, ls);
        hv[j] = (short)hs; lv[j] = (short)ls;
      }
      *(short8*)&phi[f << 3] = hv;
      *(short8*)&plo[f << 3] = lv;
    }
  }
  __syncthreads();
  short8 Gh0 = *(const short8*)&ghi[((0 + wv) << 6 | lane) << 3];
  short8 Gl0 = *(const short8*)&glo[((0 + wv) << 6 | lane) << 3];
  short8 Gh1 = *(const short8*)&ghi[((4 + wv) << 6 | lane) << 3];
  short8 Gl1 = *(const short8*)&glo[((4 + wv) << 6 | lane) << 3];
  short8 Ph0, Pl0, Ph1, Pl1;
  if (HASP) {
    Ph0 = *(const short8*)&phi[((0 + wv) << 6 | lane) << 3];
    Pl0 = *(const short8*)&plo[((0 + wv) << 6 | lane) << 3];
    Ph1 = *(const short8*)&phi[((4 + wv) << 6 | lane) << 3];
    Pl1 = *(const short8*)&plo[((4 + wv) << 6 | lane) << 3];
  }
  int nl = lane & 15;
  f32x4 acc[12];
#pragma unroll
  for (int g = 0; g < 6; ++g)
#pragma unroll
    for (int ct2 = 0; ct2 < 2; ++ct2) {
      int c = (((ch << 1) + ct2) << 4) + nl;
      float b = (g < 3) ? bih[(g << 6) + c] : bhh[((g - 3) << 6) + c];
      acc[(g << 1) + ct2] = (f32x4){b, b, b, b};
    }
#pragma unroll
  for (int g = 0; g < 3; ++g)
#pragma unroll
    for (int ct2 = 0; ct2 < 2; ++ct2) {
      int t = (g << 2) + (ch << 1) + ct2;
      const short8* bh0p = (const short8*)(WGhi + ((t << 1) << 9)) + lane;
      const short8* bl0p = (const short8*)(WGlo + ((t << 1) << 9)) + lane;
      const short8* bh1p = (const short8*)(WGhi + (((t << 1) + 1) << 9)) + lane;
      const short8* bl1p = (const short8*)(WGlo + (((t << 1) + 1) << 9)) + lane;
      short8 bh0 = *bh0p, bl0 = *bl0p, bh1 = *bh1p, bl1 = *bl1p;
      int a = (g << 1) + ct2;
      acc[a] = MFMA16(Gh0, bh0, acc[a], 0, 0, 0);
      acc[a] = MFMA16(Gh0, bl0, acc[a], 0, 0, 0);
      acc[a] = MFMA16(Gl0, bh0, acc[a], 0, 0, 0);
      acc[a] = MFMA16(Gh1, bh1, acc[a], 0, 0, 0);
      acc[a] = MFMA16(Gh1, bl1, acc[a], 0, 0, 0);
      acc[a] = MFMA16(Gl1, bh1, acc[a], 0, 0, 0);
    }
  if (HASP) {
#pragma unroll
    for (int g = 0; g < 3; ++g)
#pragma unroll
      for (int ct2 = 0; ct2 < 2; ++ct2) {
        int t = 12 + (g << 2) + (ch << 1) + ct2;
        const short8* bh0p = (const short8*)(WGhi + ((t << 1) << 9)) + lane;
        const short8* bl0p = (const short8*)(WGlo + ((t << 1) << 9)) + lane;
        const short8* bh1p = (const short8*)(WGhi + (((t << 1) + 1) << 9)) + lane;
        const short8* bl1p = (const short8*)(WGlo + (((t << 1) + 1) << 9)) + lane;
        short8 bh0 = *bh0p, bl0 = *bl0p, bh1 = *bh1p, bl1 = *bl1p;
        int a = 6 + (g << 1) + ct2;
        acc[a] = MFMA16(Ph0, bh0, acc[a], 0, 0, 0);
        acc[a] = MFMA16(Ph0, bl0, acc[a], 0, 0, 0);
        acc[a] = MFMA16(Pl0, bh0, acc[a], 0, 0, 0);
        acc[a] = MFMA16(Ph1, bh1, acc[a], 0, 0, 0);
        acc[a] = MFMA16(Ph1, bl1, acc[a], 0, 0, 0);
        acc[a] = MFMA16(Pl1, bh1, acc[a], 0, 0, 0);
      }
  }
  int rbase = (wv << 4) + ((lane >> 4) << 2);
#pragma unroll
  for (int ct2 = 0; ct2 < 2; ++ct2) {
    int c = (((ch << 1) + ct2) << 4) + nl;
    int cl = (ct2 << 4) + nl;
#pragma unroll
    for (int reg = 0; reg < 4; ++reg) {
      size_t rowg = m0 + rbase + reg;
      float rg = sigf(acc[ct2][reg]      + acc[6 + ct2][reg]);
      float zg = sigf(acc[2 + ct2][reg]  + acc[8 + ct2][reg]);
      float ng = tanhfast(acc[4 + ct2][reg] + rg * acc[10 + ct2][reg]);
      float hv = HASP ? hp[(rowg << 6) + c] : 0.f;
      cbuf[(rbase + reg) * GST + cl] = (1.f - zg) * ng + zg * hv;
    }
  }
  __syncthreads();
#pragma unroll
  for (int i = 0; i < 2; ++i) {
    int idx = (i << 10) + (tid << 2);
    int row = idx >> 5, col = idx & 31;
    *(float4*)(hout + ((m0 + row) << 6) + (ch << 5) + col) = *(float4*)&cbuf[row * GST + col];
  }
}

// ---------------------------------------------------------------------------
// Heads v2 (R17, measured good).
// ---------------------------------------------------------------------------
__global__ __launch_bounds__(256) void k_heads(
    const float* __restrict__ Xb,
    const float* __restrict__ oW1, const float* __restrict__ ob1,
    const float* __restrict__ oW2, const float* __restrict__ ob2,
    const float* __restrict__ dW1, const float* __restrict__ db1,
    const float* __restrict__ dW2, const float* __restrict__ db2,
    float* __restrict__ out) {
  __shared__ float xa[64 * 65];
  __shared__ float w1o[64 * 32], w1d[64 * 32];
  __shared__ float po[4][64], pd[4][64];
  int tid = threadIdx.x;
  int rblk = blockIdx.x << 6;
  int b = rblk >> 11;
  int n0 = rblk & (Nn - 1);
  const float* src = Xb + (((size_t)b * Ss + (Ss - 1)) * Nn + n0) * Hh;
#pragma unroll
  for (int i = 0; i < 4; ++i) {
    int idx = (i << 10) + (tid << 2);
    int row = idx >> 6, col = idx & 63;
    float4 v = *(const float4*)(src + idx);
    float* dp = &xa[row * 65 + col];
    dp[0] = v.x; dp[1] = v.y; dp[2] = v.z; dp[3] = v.w;
  }
  for (int idx = tid; idx < 2048; idx += 256) {
    w1o[idx] = oW1[idx];
    w1d[idx] = dW1[idx];
  }
  __syncthreads();
  int row = tid & 63;
  int jg = tid >> 6;
  int j0 = jg << 3;
  float hO[8], hD[8];
#pragma unroll
  for (int j = 0; j < 8; ++j) { hO[j] = ob1[j0 + j]; hD[j] = db1[j0 + j]; }
  const float* xr = &xa[row * 65];
  for (int k = 0; k < 64; ++k) {
    float xv = xr[k];
    const float4* wo = (const float4*)&w1o[(k << 5) + j0];
    const float4* wd = (const float4*)&w1d[(k << 5) + j0];
    float4 o0 = wo[0], o1 = wo[1], d0 = wd[0], d1 = wd[1];
    hO[0] = fmaf(xv, o0.x, hO[0]); hO[1] = fmaf(xv, o0.y, hO[1]);
    hO[2] = fmaf(xv, o0.z, hO[2]); hO[3] = fmaf(xv, o0.w, hO[3]);
    hO[4] = fmaf(xv, o1.x, hO[4]); hO[5] = fmaf(xv, o1.y, hO[5]);
    hO[6] = fmaf(xv, o1.z, hO[6]); hO[7] = fmaf(xv, o1.w, hO[7]);
    hD[0] = fmaf(xv, d0.x, hD[0]); hD[1] = fmaf(xv, d0.y, hD[1]);
    hD[2] = fmaf(xv, d0.z, hD[2]); hD[3] = fmaf(xv, d0.w, hD[3]);
    hD[4] = fmaf(xv, d1.x, hD[4]); hD[5] = fmaf(xv, d1.y, hD[5]);
    hD[6] = fmaf(xv, d1.z, hD[6]); hD[7] = fmaf(xv, d1.w, hD[7]);
  }
  float accoP = 0.f, accdP = 0.f;
#pragma unroll
  for (int j = 0; j < 8; ++j) {
    accoP = fmaf(fmaxf(hO[j], 0.f), oW2[j0 + j], accoP);
    accdP = fmaf(fmaxf(hD[j], 0.f), dW2[j0 + j], accdP);
  }
  po[jg][row] = accoP;
  pd[jg][row] = accdP;
  __syncthreads();
  if (tid < 64) {
    int r = rblk + tid;
    out[r]           = ob2[0] + ((po[0][tid] + po[1][tid]) + (po[2][tid] + po[3][tid]));
    out[Bb * Nn + r] = db2[0] + ((pd[0][tid] + pd[1][tid]) + (pd[2][tid] + pd[3][tid]));
  }
}

// ---------------------------------------------------------------------------
extern "C" void kernel_launch(void* const* d_in, const int* in_sizes, int n_in,
                              void* d_out, int out_size, void* d_ws, size_t ws_size,
                              hipStream_t stream) {
  const float* x   = (const float*)d_in[0];
  const int*   ei  = (const int*)d_in[1];
  const float* ea  = (const float*)d_in[2];
  const float* Wp  = (const float*)d_in[3];
  const float* bp  = (const float*)d_in[4];
  const float* Wl  = (const float*)d_in[5];
  const float* bl  = (const float*)d_in[6];
  const float* Wr  = (const float*)d_in[7];
  const float* br  = (const float*)d_in[8];
  const float* We  = (const float*)d_in[9];
  const float* att = (const float*)d_in[10];
  const float* gb  = (const float*)d_in[11];
  const float* Wih = (const float*)d_in[12];
  const float* Whh = (const float*)d_in[13];
  const float* bih = (const float*)d_in[14];
  const float* bhh = (const float*)d_in[15];
  const float* oW1 = (const float*)d_in[16];
  const float* ob1 = (const float*)d_in[17];
  const float* oW2 = (const float*)d_in[18];
  const float* ob2 = (const float*)d_in[19];
  const float* dW1 = (const float*)d_in[20];
  const float* db1 = (const float*)d_in[21];
  const float* dW2 = (const float*)d_in[22];
  const float* db2 = (const float*)d_in[23];
  float* out = (float*)d_out;

  // workspace layout
  float* f    = (float*)d_ws;
  float* Xb   = f;                          // RTOT*64
  float* XLb  = Xb  + (size_t)RTOT * Hh;
  float* XRb  = XLb + (size_t)RTOT * Hh;    // hg after k_gat
  float* EPc  = XRb + (size_t)RTOT * Hh;    // 2 * E2c * 64 (CSR order, both layers)
  unsigned short* WXhi = (unsigned short*)(EPc + (size_t)2 * E2c * Hh); // 16384
  unsigned short* WXlo = WXhi + 16384;
  unsigned short* WGhi = WXlo + 16384;      // 49152
  unsigned short* WGlo = WGhi + 49152;
  float* cntF = (float*)(WGlo + 49152);     // 2048
  float* loopA = cntF + Nn;                 // 2048*8
  int*   fillI = (int*)(loopA + Nn * EFf);  // 2048
  int*   offs  = fillI + Nn;                // 2049 (+pad)
  int*   posOf = offs + 2052;               // 18432
  int*   srcA  = posOf + E2c;               // 18432

  hipMemsetAsync(cntF, 0, (size_t)(Nn + Nn * EFf + Nn) * 4, stream);

  k_loop_accum<<<dim3(Ee * EFf / 256), 256, 0, stream>>>(ei, ea, cntF, loopA);
  k_scan<<<1, 256, 0, stream>>>(cntF, offs);
  k_scatter<<<dim3((E2c + 255) / 256), 256, 0, stream>>>(ei, offs, fillI, posOf, srcA);
  k_wprep<<<dim3(256), 256, 0, stream>>>(Wl, Wr, Wih, Whh, WXhi, WXlo, WGhi, WGlo);

  // X = x @ Wp + bp
  k_proj<<<dim3(RTOT / 512, 4), 256, 0, stream>>>(x, Wp, bp, Xb);

  // ep for both layers (division by cnt folded in)
  k_ep<<<dim3(E2c * Hh / 256, 2), 256, 0, stream>>>(ea, loopA, We, posOf, cntF, EPc);

  for (int l = 0; l < 2; ++l) {
    k_xlr_mm<<<dim3(RTOT / 64), 256, 0, stream>>>(
        Xb, WXhi + (size_t)l * 8192, WXlo + (size_t)l * 8192,
        bl + (size_t)l * Hh, br + (size_t)l * Hh, XLb, XRb);
    k_gat<<<dim3(Nn, 4), 256, 0, stream>>>(
        XLb, XRb, EPc + (size_t)l * E2c * Hh, offs, srcA,
        att + (size_t)l * Hh, gb + (size_t)l * Hh);
    const unsigned short* WGh_l = WGhi + (size_t)l * 24576;
    const unsigned short* WGl_l = WGlo + (size_t)l * 24576;
    const float* bih_l = bih + (size_t)l * 192;
    const float* bhh_l = bhh + (size_t)l * 192;
    for (int t = 0; t < Bb; ++t) {
      const float* hg_t = XRb + (size_t)t * Mm * Hh;
      float* h_out = Xb + (size_t)t * Mm * Hh;
      if (t == 0) {
        k_gru_mm<0><<<dim3(Mm / 64, 2), 256, 0, stream>>>(
            hg_t, nullptr, WGh_l, WGl_l, bih_l, bhh_l, h_out);
      } else {
        const float* h_prev = Xb + (size_t)(t - 1) * Mm * Hh;
        k_gru_mm<1><<<dim3(Mm / 64, 2), 256, 0, stream>>>(
            hg_t, h_prev, WGh_l, WGl_l, bih_l, bhh_l, h_out);
      }
    }
  }

  k_heads<<<dim3(Bb * Nn / 64), 256, 0, stream>>>(
      Xb, oW1, ob1, oW2, ob2, dW1, db1, dW2, db2, out);
}